// Round 3
// baseline (549.313 us; speedup 1.0000x reference)
//
#include <hip/hip_runtime.h>
#include <cstdint>
#include <cstddef>

#define N_TOKENS 4096
#define HIDDEN   2048
#define INTER    1024
#define NE       8
#define NE_TOT   10
#define SCALE    2.5f

typedef short v8s __attribute__((ext_vector_type(8)));
typedef float v4f __attribute__((ext_vector_type(4)));

static __device__ inline int imin(int a, int b) { return a < b ? a : b; }

__device__ inline unsigned short f2bf(float f) {
  unsigned int u = __float_as_uint(f);
  u += 0x7fffu + ((u >> 16) & 1u);   // round-to-nearest-even
  return (unsigned short)(u >> 16);
}

__device__ inline void gld_lds16(const void* g, void* l) {
  __builtin_amdgcn_global_load_lds(
      (const __attribute__((address_space(1))) unsigned int*)g,
      (__attribute__((address_space(3))) unsigned int*)l, 16, 0, 0);
}

// T4 pipeline primitives: raw barrier + counted vmcnt (never 0 in main loop).
// "memory" clobbers pin compiler ordering of ds_read/global_load_lds around them.
#define FENCE() __asm__ __volatile__("" ::: "memory")
#define BAR()   do { FENCE(); __builtin_amdgcn_s_barrier(); FENCE(); } while (0)
#define WAITVM(n) __asm__ __volatile__("s_waitcnt vmcnt(" #n ")" ::: "memory")
#define WAITLGKM0() __asm__ __volatile__("s_waitcnt lgkmcnt(0)" ::: "memory")

// ---------------- init: zero per-expert counts ----------------
__global__ void init_kernel(int* counts) {
  if (threadIdx.x < NE) counts[threadIdx.x] = 0;
}

// ---------------- f32 -> bf16 weight conversion ----------------
__global__ __launch_bounds__(256) void cvt_kernel(const float* __restrict__ src,
                                                  unsigned short* __restrict__ dst,
                                                  int n8) {
  int i = blockIdx.x * 256 + threadIdx.x;
  if (i >= n8) return;
  size_t b = (size_t)i * 8;
  float4 a0 = *(const float4*)(src + b);
  float4 a1 = *(const float4*)(src + b + 4);
  union { unsigned short u[8]; uint4 v; } r;
  r.u[0] = f2bf(a0.x); r.u[1] = f2bf(a0.y); r.u[2] = f2bf(a0.z); r.u[3] = f2bf(a0.w);
  r.u[4] = f2bf(a1.x); r.u[5] = f2bf(a1.y); r.u[6] = f2bf(a1.z); r.u[7] = f2bf(a1.w);
  *(uint4*)(dst + b) = r.v;
}

// ---------------- router: no-LDS, 1 token per wave, fused x->bf16 and out = wz*x ----
__global__ __launch_bounds__(256, 4) void router_kernel(
    const float* __restrict__ x, const float* __restrict__ rw,
    const float* __restrict__ bias, unsigned short* __restrict__ xb,
    int* __restrict__ counts, int* __restrict__ tok_list,
    float* __restrict__ tok_w, float* __restrict__ out) {
  int tid  = threadIdx.x;
  int lane = tid & 63;
  int wid  = tid >> 6;
  int n    = blockIdx.x * 4 + wid;

  const float* xr = x + (size_t)n * HIDDEN;
  float4 xv[8];
#pragma unroll
  for (int i = 0; i < 8; i++) xv[i] = *(const float4*)(xr + (i * 64 + lane) * 4);

  float acc[NE_TOT];
#pragma unroll
  for (int e = 0; e < NE_TOT; e++) {
    const float* wr = rw + (size_t)e * HIDDEN;
    float a = 0.f;
#pragma unroll
    for (int i = 0; i < 8; i++) {
      float4 w = *(const float4*)(wr + (i * 64 + lane) * 4);
      a += xv[i].x * w.x + xv[i].y * w.y + xv[i].z * w.z + xv[i].w * w.w;
    }
    acc[e] = a;
  }
#pragma unroll
  for (int e = 0; e < NE_TOT; e++) {
    float v = acc[e];
#pragma unroll
    for (int off = 32; off > 0; off >>= 1) v += __shfl_xor(v, off, 64);
    acc[e] = v;  // all lanes hold the full dot product
  }

  // sigmoid + bias, top-2 (ties -> lower index), redundantly on all lanes
  float sc[NE_TOT], sb[NE_TOT];
#pragma unroll
  for (int e = 0; e < NE_TOT; e++) {
    sc[e] = 1.f / (1.f + expf(-acc[e]));
    sb[e] = sc[e] + bias[e];
  }
  int i1 = 0;
  for (int e = 1; e < NE_TOT; e++) if (sb[e] > sb[i1]) i1 = e;
  int i2 = (i1 == 0) ? 1 : 0;
  for (int e = 0; e < NE_TOT; e++) if (e != i1 && sb[e] > sb[i2]) i2 = e;
  float wzero = 0.f;
  if (i1 >= NE) wzero += sc[i1];
  if (i2 >= NE) wzero += sc[i2];
  if (lane == 0) {
#pragma unroll
    for (int tt = 0; tt < 2; tt++) {
      int idx = tt == 0 ? i1 : i2;
      if (idx < NE) {
        int slot = atomicAdd(&counts[idx], 1);
        tok_list[idx * N_TOKENS + slot] = n;
        tok_w[idx * N_TOKENS + slot]    = SCALE * sc[idx];
      }
    }
  }
  float wz = SCALE * wzero;
  // fused stores: xb (bf16) and out = wz*x
#pragma unroll
  for (int i = 0; i < 8; i++) {
    int k = (i * 64 + lane) * 4;
    ushort4 ob;
    ob.x = f2bf(xv[i].x); ob.y = f2bf(xv[i].y);
    ob.z = f2bf(xv[i].z); ob.w = f2bf(xv[i].w);
    *(ushort4*)(xb + (size_t)n * HIDDEN + k) = ob;
    float4 o;
    o.x = wz * xv[i].x; o.y = wz * xv[i].y; o.z = wz * xv[i].z; o.w = wz * xv[i].w;
    *(float4*)(out + (size_t)n * HIDDEN + k) = o;
  }
}

// ---------------- prefix offsets over counts ----------------
__global__ void offsets_kernel(const int* __restrict__ counts, int* __restrict__ offsets) {
  if (threadIdx.x == 0) {
    int s = 0;
    for (int e = 0; e < NE; e++) { offsets[e] = s; s += counts[e]; }
  }
}

// LDS xor-swizzle (kills 8-way ds_read_b128 bank conflicts):
// physical 16B chunk p of row r holds logical chunk p ^ ((r>>1)&3).
// Staging (lane tid -> row tid>>2, slot tid&3): fetch global chunk
// (tid&3) ^ ((tid>>3)&3). Readers: physical chunk (lane>>4) ^ ((lane>>1)&3).
//
// T4 3-deep pipeline: compute tile kt from buf[kt%3]; BAR (WAR: all waves
// done reading); stage tile kt+3 into the freed buffer; vmcnt(8) waits only
// for tile kt+1's loads (issued 2 iters ago -> already landed); BAR (RAW:
// every wave's kt+1 stage visible). Loads stay in flight across barriers.

// ---------------- gate_up grouped GEMM + fused SiLU*up ----------------
__global__ __launch_bounds__(256, 3) void gateup_kernel(
    const unsigned short* __restrict__ xb, const unsigned short* __restrict__ wgu,
    const int* __restrict__ counts, const int* __restrict__ offsets,
    const int* __restrict__ tok_list, unsigned short* __restrict__ h_buf) {
  int jt = blockIdx.x;  // 16: f-block of 64
  int mt = blockIdx.y;  // 32: token tile of 128
  int e  = blockIdx.z;  // 8
  int count = counts[e];
  if (mt * 128 >= count) return;

  __shared__ unsigned short As[3][128 * 32];
  __shared__ unsigned short Bs[3][128 * 32];

  int tid  = threadIdx.x;
  int lane = tid & 63;
  int wm = (tid >> 7) & 1;
  int wn = (tid >> 6) & 1;

  int row0 = tid >> 2, row1 = row0 + 64;
  int col8 = (((tid & 3) ^ ((tid >> 3) & 3)) * 8);  // swizzled source chunk

  const int* tl = tok_list + e * N_TOKENS;
  int t0 = tl[imin(mt * 128 + row0, count - 1)];
  int t1 = tl[imin(mt * 128 + row1, count - 1)];
  const unsigned short* ag0 = xb + (size_t)t0 * HIDDEN + col8;
  const unsigned short* ag1 = xb + (size_t)t1 * HIDDEN + col8;

  int wn0 = row0 >> 6, wi0 = row0 & 63;
  int wn1 = row1 >> 6, wi1 = row1 & 63;
  int br0 = (wi0 < 32) ? (jt * 64 + wn0 * 32 + wi0) : (1024 + jt * 64 + wn0 * 32 + (wi0 - 32));
  int br1 = (wi1 < 32) ? (jt * 64 + wn1 * 32 + wi1) : (1024 + jt * 64 + wn1 * 32 + (wi1 - 32));
  const unsigned short* bbase = wgu + (size_t)e * (2 * INTER) * HIDDEN;
  const unsigned short* bg0 = bbase + (size_t)br0 * HIDDEN + col8;
  const unsigned short* bg1 = bbase + (size_t)br1 * HIDDEN + col8;

  auto STAGE = [&](int b) {
    gld_lds16(ag0, &As[b][(size_t)tid * 8]);
    gld_lds16(ag1, &As[b][2048 + (size_t)tid * 8]);
    gld_lds16(bg0, &Bs[b][(size_t)tid * 8]);
    gld_lds16(bg1, &Bs[b][2048 + (size_t)tid * 8]);
    ag0 += 32; ag1 += 32; bg0 += 32; bg1 += 32;
  };

  v4f acc[4][4];
#pragma unroll
  for (int i = 0; i < 4; i++)
#pragma unroll
    for (int j = 0; j < 4; j++) acc[i][j] = v4f{0.f, 0.f, 0.f, 0.f};

  int mrow = wm * 64 + (lane & 15);
  int nrow = wn * 64 + (lane & 15);
  int kcol = (((lane >> 4) ^ ((lane >> 1) & 3)) * 8);  // swizzled read chunk

  // prologue: stage tiles 0,1,2; wait tile 0; barrier
  STAGE(0); STAGE(1); STAGE(2);
  WAITVM(8);
  BAR();

  const int NK = HIDDEN / 32;
  for (int kt = 0; kt < NK; kt++) {
    int cur = kt % 3;
    v8s a[4], b[4];
#pragma unroll
    for (int i = 0; i < 4; i++) a[i] = *(const v8s*)&As[cur][(mrow + i * 16) * 32 + kcol];
#pragma unroll
    for (int j = 0; j < 4; j++) b[j] = *(const v8s*)&Bs[cur][(nrow + j * 16) * 32 + kcol];
#pragma unroll
    for (int i = 0; i < 4; i++)
#pragma unroll
      for (int j = 0; j < 4; j++)
        acc[i][j] = __builtin_amdgcn_mfma_f32_16x16x32_bf16(a[i], b[j], acc[i][j], 0, 0, 0);
    WAITLGKM0();
    BAR();  // WAR: all waves finished reading buf[cur]
    if (kt + 3 < NK)      { STAGE(cur); WAITVM(8); }
    else if (kt + 3 == NK){ WAITVM(4); }
    else if (kt + 1 < NK) { WAITVM(0); }
    if (kt + 1 < NK) BAR();  // RAW: tile kt+1 fully resident
  }

  int ocol  = lane & 15;
  int orow4 = (lane >> 4) * 4;
  int hoff  = offsets[e];
#pragma unroll
  for (int i = 0; i < 4; i++) {
#pragma unroll
    for (int r = 0; r < 4; r++) {
      int m = mt * 128 + wm * 64 + i * 16 + orow4 + r;
      if (m < count) {
        unsigned short* hrow = h_buf + (size_t)(hoff + m) * INTER;
#pragma unroll
        for (int j = 0; j < 2; j++) {
          float g = acc[i][j][r];
          float u = acc[i][j + 2][r];
          float hv = (g / (1.f + expf(-g))) * u;
          hrow[jt * 64 + wn * 32 + j * 16 + ocol] = f2bf(hv);
        }
      }
    }
  }
}

// ---------------- down grouped GEMM, scatter-add into out ----------------
__global__ __launch_bounds__(256, 3) void down_kernel(
    const unsigned short* __restrict__ h_buf, const unsigned short* __restrict__ wd,
    const int* __restrict__ counts, const int* __restrict__ offsets,
    const int* __restrict__ tok_list, const float* __restrict__ tok_w,
    float* __restrict__ out) {
  int nt = blockIdx.x;  // 16: out-col tile of 128
  int mt = blockIdx.y;  // 32
  int e  = blockIdx.z;  // 8
  int count = counts[e];
  if (mt * 128 >= count) return;

  __shared__ unsigned short As[3][128 * 32];
  __shared__ unsigned short Bs[3][128 * 32];

  int tid  = threadIdx.x;
  int lane = tid & 63;
  int wm = (tid >> 7) & 1;
  int wn = (tid >> 6) & 1;

  int row0 = tid >> 2, row1 = row0 + 64;
  int col8 = (((tid & 3) ^ ((tid >> 3) & 3)) * 8);
  int hoff = offsets[e];

  const unsigned short* ag0 =
      h_buf + (size_t)(hoff + imin(mt * 128 + row0, count - 1)) * INTER + col8;
  const unsigned short* ag1 =
      h_buf + (size_t)(hoff + imin(mt * 128 + row1, count - 1)) * INTER + col8;
  const unsigned short* bbase = wd + (size_t)e * HIDDEN * INTER;
  const unsigned short* bg0 = bbase + (size_t)(nt * 128 + row0) * INTER + col8;
  const unsigned short* bg1 = bbase + (size_t)(nt * 128 + row1) * INTER + col8;

  auto STAGE = [&](int b) {
    gld_lds16(ag0, &As[b][(size_t)tid * 8]);
    gld_lds16(ag1, &As[b][2048 + (size_t)tid * 8]);
    gld_lds16(bg0, &Bs[b][(size_t)tid * 8]);
    gld_lds16(bg1, &Bs[b][2048 + (size_t)tid * 8]);
    ag0 += 32; ag1 += 32; bg0 += 32; bg1 += 32;
  };

  v4f acc[4][4];
#pragma unroll
  for (int i = 0; i < 4; i++)
#pragma unroll
    for (int j = 0; j < 4; j++) acc[i][j] = v4f{0.f, 0.f, 0.f, 0.f};

  int mrow = wm * 64 + (lane & 15);
  int nrow = wn * 64 + (lane & 15);
  int kcol = (((lane >> 4) ^ ((lane >> 1) & 3)) * 8);

  // prologue: stage tiles 0,1,2; wait tile 0; barrier
  STAGE(0); STAGE(1); STAGE(2);
  WAITVM(8);
  BAR();

  const int NK = INTER / 32;
  for (int kt = 0; kt < NK; kt++) {
    int cur = kt % 3;
    v8s a[4], b[4];
#pragma unroll
    for (int i = 0; i < 4; i++) a[i] = *(const v8s*)&As[cur][(mrow + i * 16) * 32 + kcol];
#pragma unroll
    for (int j = 0; j < 4; j++) b[j] = *(const v8s*)&Bs[cur][(nrow + j * 16) * 32 + kcol];
#pragma unroll
    for (int i = 0; i < 4; i++)
#pragma unroll
      for (int j = 0; j < 4; j++)
        acc[i][j] = __builtin_amdgcn_mfma_f32_16x16x32_bf16(a[i], b[j], acc[i][j], 0, 0, 0);
    WAITLGKM0();
    BAR();  // WAR: all waves finished reading buf[cur]
    if (kt + 3 < NK)      { STAGE(cur); WAITVM(8); }
    else if (kt + 3 == NK){ WAITVM(4); }
    else if (kt + 1 < NK) { WAITVM(0); }
    if (kt + 1 < NK) BAR();  // RAW: tile kt+1 fully resident
  }

  int ocol  = lane & 15;
  int orow4 = (lane >> 4) * 4;
#pragma unroll
  for (int i = 0; i < 4; i++) {
#pragma unroll
    for (int r = 0; r < 4; r++) {
      int m = mt * 128 + wm * 64 + i * 16 + orow4 + r;
      if (m < count) {
        int tok  = tok_list[e * N_TOKENS + m];
        float w  = tok_w[e * N_TOKENS + m];
        float* orow = out + (size_t)tok * HIDDEN + nt * 128 + wn * 64 + ocol;
#pragma unroll
        for (int j = 0; j < 4; j++) atomicAdd(orow + j * 16, acc[i][j][r] * w);
      }
    }
  }
}

extern "C" void kernel_launch(void* const* d_in, const int* in_sizes, int n_in,
                              void* d_out, int out_size, void* d_ws, size_t ws_size,
                              hipStream_t stream) {
  const float* x   = (const float*)d_in[0];
  const float* rw  = (const float*)d_in[1];
  const float* cb  = (const float*)d_in[2];
  const float* wgu = (const float*)d_in[3];
  const float* wd  = (const float*)d_in[4];
  float* out = (float*)d_out;

  char* ws = (char*)d_ws;
  size_t off = 0;
  auto alloc = [&](size_t bytes) {
    void* p = ws + off;
    off += (bytes + 255) & ~(size_t)255;
    return p;
  };
  unsigned short* xb    = (unsigned short*)alloc((size_t)N_TOKENS * HIDDEN * 2);
  unsigned short* wgu_b = (unsigned short*)alloc((size_t)NE * 2 * INTER * HIDDEN * 2);
  unsigned short* wd_b  = (unsigned short*)alloc((size_t)NE * HIDDEN * INTER * 2);
  unsigned short* h_buf = (unsigned short*)alloc((size_t)2 * N_TOKENS * INTER * 2);
  int*   tok_list = (int*)alloc((size_t)NE * N_TOKENS * 4);
  float* tok_w    = (float*)alloc((size_t)NE * N_TOKENS * 4);
  int*   counts   = (int*)alloc(256);
  int*   offsets  = (int*)alloc(256);
  (void)ws_size; (void)in_sizes; (void)n_in; (void)out_size;

  init_kernel<<<1, 64, 0, stream>>>(counts);
  cvt_kernel<<<(NE * 2 * INTER * HIDDEN / 8 + 255) / 256, 256, 0, stream>>>(
      wgu, wgu_b, NE * 2 * INTER * HIDDEN / 8);
  cvt_kernel<<<(NE * HIDDEN * INTER / 8 + 255) / 256, 256, 0, stream>>>(
      wd, wd_b, NE * HIDDEN * INTER / 8);
  router_kernel<<<N_TOKENS / 4, 256, 0, stream>>>(x, rw, cb, xb, counts, tok_list, tok_w, out);
  offsets_kernel<<<1, 64, 0, stream>>>(counts, offsets);
  gateup_kernel<<<dim3(16, 32, 8), 256, 0, stream>>>(xb, wgu_b, counts, offsets, tok_list, h_buf);
  down_kernel<<<dim3(16, 32, 8), 256, 0, stream>>>(h_buf, wd_b, counts, offsets, tok_list, tok_w, out);
}

// Round 4
// 523.298 us; speedup vs baseline: 1.0497x; 1.0497x over previous
//
#include <hip/hip_runtime.h>
#include <cstdint>
#include <cstddef>

#define N_TOKENS 4096
#define HIDDEN   2048
#define INTER    1024
#define NE       8
#define NE_TOT   10
#define SCALE    2.5f

typedef short v8s __attribute__((ext_vector_type(8)));
typedef float v4f __attribute__((ext_vector_type(4)));

static __device__ inline int imin(int a, int b) { return a < b ? a : b; }

__device__ inline unsigned short f2bf(float f) {
  unsigned int u = __float_as_uint(f);
  u += 0x7fffu + ((u >> 16) & 1u);   // round-to-nearest-even
  return (unsigned short)(u >> 16);
}

__device__ inline void gld_lds16(const void* g, void* l) {
  __builtin_amdgcn_global_load_lds(
      (const __attribute__((address_space(1))) unsigned int*)g,
      (__attribute__((address_space(3))) unsigned int*)l, 16, 0, 0);
}

// ---------------- init: zero per-expert counts ----------------
__global__ void init_kernel(int* counts) {
  if (threadIdx.x < NE) counts[threadIdx.x] = 0;
}

// ---------------- f32 -> bf16 weight conversion ----------------
__global__ __launch_bounds__(256) void cvt_kernel(const float* __restrict__ src,
                                                  unsigned short* __restrict__ dst,
                                                  int n8) {
  int i = blockIdx.x * 256 + threadIdx.x;
  if (i >= n8) return;
  size_t b = (size_t)i * 8;
  float4 a0 = *(const float4*)(src + b);
  float4 a1 = *(const float4*)(src + b + 4);
  union { unsigned short u[8]; uint4 v; } r;
  r.u[0] = f2bf(a0.x); r.u[1] = f2bf(a0.y); r.u[2] = f2bf(a0.z); r.u[3] = f2bf(a0.w);
  r.u[4] = f2bf(a1.x); r.u[5] = f2bf(a1.y); r.u[6] = f2bf(a1.z); r.u[7] = f2bf(a1.w);
  *(uint4*)(dst + b) = r.v;
}

// ---------------- router v3: two-pass, low-VGPR, no spill ----------------
// Pass 1 streams x+rw with transient registers (acc[10] only live state);
// pass 2 re-reads the 8KB x row (L1/L2-hot) for the xb/out stores. This
// replaces the R1 structure whose xv[8]+unrolled-w working set (~200 VGPR)
// spilled to scratch under the launch-bounds cap.
__global__ __launch_bounds__(256, 4) void router_kernel(
    const float* __restrict__ x, const float* __restrict__ rw,
    const float* __restrict__ bias, unsigned short* __restrict__ xb,
    int* __restrict__ counts, int* __restrict__ tok_list,
    float* __restrict__ tok_w, float* __restrict__ out) {
  int tid  = threadIdx.x;
  int lane = tid & 63;
  int wid  = tid >> 6;
  int n    = blockIdx.x * 4 + wid;

  const float* xr = x + (size_t)n * HIDDEN;
  float acc[NE_TOT];
#pragma unroll
  for (int e = 0; e < NE_TOT; e++) acc[e] = 0.f;

#pragma unroll 1
  for (int i = 0; i < 8; i++) {
    int k = (i * 64 + lane) * 4;
    float4 xv = *(const float4*)(xr + k);
#pragma unroll
    for (int e = 0; e < NE_TOT; e++) {
      float4 w = *(const float4*)(rw + (size_t)e * HIDDEN + k);
      acc[e] += xv.x * w.x + xv.y * w.y + xv.z * w.z + xv.w * w.w;
    }
  }
#pragma unroll
  for (int e = 0; e < NE_TOT; e++) {
    float v = acc[e];
#pragma unroll
    for (int off = 32; off > 0; off >>= 1) v += __shfl_xor(v, off, 64);
    acc[e] = v;  // all lanes hold the full dot product
  }

  // sigmoid + bias, top-2 (ties -> lower index), redundantly on all lanes
  float sc[NE_TOT], sb[NE_TOT];
#pragma unroll
  for (int e = 0; e < NE_TOT; e++) {
    sc[e] = 1.f / (1.f + expf(-acc[e]));
    sb[e] = sc[e] + bias[e];
  }
  int i1 = 0;
  for (int e = 1; e < NE_TOT; e++) if (sb[e] > sb[i1]) i1 = e;
  int i2 = (i1 == 0) ? 1 : 0;
  for (int e = 0; e < NE_TOT; e++) if (e != i1 && sb[e] > sb[i2]) i2 = e;
  float wzero = 0.f;
  if (i1 >= NE) wzero += sc[i1];
  if (i2 >= NE) wzero += sc[i2];
  if (lane == 0) {
#pragma unroll
    for (int tt = 0; tt < 2; tt++) {
      int idx = tt == 0 ? i1 : i2;
      if (idx < NE) {
        int slot = atomicAdd(&counts[idx], 1);
        tok_list[idx * N_TOKENS + slot] = n;
        tok_w[idx * N_TOKENS + slot]    = SCALE * sc[idx];
      }
    }
  }
  float wz = SCALE * wzero;

  // pass 2: re-read x row (cache-hot), emit xb (bf16) and out = wz*x
#pragma unroll
  for (int i = 0; i < 8; i++) {
    int k = (i * 64 + lane) * 4;
    float4 xv = *(const float4*)(xr + k);
    ushort4 ob;
    ob.x = f2bf(xv.x); ob.y = f2bf(xv.y);
    ob.z = f2bf(xv.z); ob.w = f2bf(xv.w);
    *(ushort4*)(xb + (size_t)n * HIDDEN + k) = ob;
    float4 o;
    o.x = wz * xv.x; o.y = wz * xv.y; o.z = wz * xv.z; o.w = wz * xv.w;
    *(float4*)(out + (size_t)n * HIDDEN + k) = o;
  }
}

// ---------------- prefix offsets over counts ----------------
__global__ void offsets_kernel(const int* __restrict__ counts, int* __restrict__ offsets) {
  if (threadIdx.x == 0) {
    int s = 0;
    for (int e = 0; e < NE; e++) { offsets[e] = s; s += counts[e]; }
  }
}

// LDS xor-swizzle (kills 8-way ds_read_b128 bank conflicts):
// physical 16B chunk p of row r holds logical chunk p ^ ((r>>1)&3).
// Staging (lane tid -> row tid>>2, slot tid&3): fetch global chunk
// (tid&3) ^ ((tid>>3)&3). Readers: physical chunk (lane>>4) ^ ((lane>>1)&3).

// ---------------- gate_up grouped GEMM + fused SiLU*up ----------------
__global__ __launch_bounds__(256, 2) void gateup_kernel(
    const unsigned short* __restrict__ xb, const unsigned short* __restrict__ wgu,
    const int* __restrict__ counts, const int* __restrict__ offsets,
    const int* __restrict__ tok_list, unsigned short* __restrict__ h_buf) {
  int jt = blockIdx.x;  // 16: f-block of 64
  int mt = blockIdx.y;  // 32: token tile of 128
  int e  = blockIdx.z;  // 8
  int count = counts[e];
  if (mt * 128 >= count) return;

  __shared__ unsigned short As[2][128 * 32];
  __shared__ unsigned short Bs[2][128 * 32];

  int tid  = threadIdx.x;
  int lane = tid & 63;
  int wm = (tid >> 7) & 1;
  int wn = (tid >> 6) & 1;

  int row0 = tid >> 2, row1 = row0 + 64;
  int col8 = (((tid & 3) ^ ((tid >> 3) & 3)) * 8);  // swizzled source chunk

  const int* tl = tok_list + e * N_TOKENS;
  int t0 = tl[imin(mt * 128 + row0, count - 1)];
  int t1 = tl[imin(mt * 128 + row1, count - 1)];
  const unsigned short* ag0 = xb + (size_t)t0 * HIDDEN + col8;
  const unsigned short* ag1 = xb + (size_t)t1 * HIDDEN + col8;

  int wn0 = row0 >> 6, wi0 = row0 & 63;
  int wn1 = row1 >> 6, wi1 = row1 & 63;
  int br0 = (wi0 < 32) ? (jt * 64 + wn0 * 32 + wi0) : (1024 + jt * 64 + wn0 * 32 + (wi0 - 32));
  int br1 = (wi1 < 32) ? (jt * 64 + wn1 * 32 + wi1) : (1024 + jt * 64 + wn1 * 32 + (wi1 - 32));
  const unsigned short* bbase = wgu + (size_t)e * (2 * INTER) * HIDDEN;
  const unsigned short* bg0 = bbase + (size_t)br0 * HIDDEN + col8;
  const unsigned short* bg1 = bbase + (size_t)br1 * HIDDEN + col8;

  v4f acc[4][4];
#pragma unroll
  for (int i = 0; i < 4; i++)
#pragma unroll
    for (int j = 0; j < 4; j++) acc[i][j] = v4f{0.f, 0.f, 0.f, 0.f};

  int mrow = wm * 64 + (lane & 15);
  int nrow = wn * 64 + (lane & 15);
  int kcol = (((lane >> 4) ^ ((lane >> 1) & 3)) * 8);  // swizzled read chunk

  // prologue: stage tile 0 into buf 0
  gld_lds16(ag0, &As[0][(size_t)tid * 8]);
  gld_lds16(ag1, &As[0][2048 + (size_t)tid * 8]);
  gld_lds16(bg0, &Bs[0][(size_t)tid * 8]);
  gld_lds16(bg1, &Bs[0][2048 + (size_t)tid * 8]);
  ag0 += 32; ag1 += 32; bg0 += 32; bg1 += 32;
  __syncthreads();

  const int NK = HIDDEN / 32;
  for (int kt = 0; kt < NK; kt++) {
    int cur = kt & 1;
    if (kt + 1 < NK) {
      int nxt = cur ^ 1;
      gld_lds16(ag0, &As[nxt][(size_t)tid * 8]);
      gld_lds16(ag1, &As[nxt][2048 + (size_t)tid * 8]);
      gld_lds16(bg0, &Bs[nxt][(size_t)tid * 8]);
      gld_lds16(bg1, &Bs[nxt][2048 + (size_t)tid * 8]);
      ag0 += 32; ag1 += 32; bg0 += 32; bg1 += 32;
    }
    v8s a[4], b[4];
#pragma unroll
    for (int i = 0; i < 4; i++) a[i] = *(const v8s*)&As[cur][(mrow + i * 16) * 32 + kcol];
#pragma unroll
    for (int j = 0; j < 4; j++) b[j] = *(const v8s*)&Bs[cur][(nrow + j * 16) * 32 + kcol];
#pragma unroll
    for (int i = 0; i < 4; i++)
#pragma unroll
      for (int j = 0; j < 4; j++)
        acc[i][j] = __builtin_amdgcn_mfma_f32_16x16x32_bf16(a[i], b[j], acc[i][j], 0, 0, 0);
    __syncthreads();
  }

  int ocol  = lane & 15;
  int orow4 = (lane >> 4) * 4;
  int hoff  = offsets[e];
#pragma unroll
  for (int i = 0; i < 4; i++) {
#pragma unroll
    for (int r = 0; r < 4; r++) {
      int m = mt * 128 + wm * 64 + i * 16 + orow4 + r;
      if (m < count) {
        unsigned short* hrow = h_buf + (size_t)(hoff + m) * INTER;
#pragma unroll
        for (int j = 0; j < 2; j++) {
          float g = acc[i][j][r];
          float u = acc[i][j + 2][r];
          float hv = (g / (1.f + expf(-g))) * u;
          hrow[jt * 64 + wn * 32 + j * 16 + ocol] = f2bf(hv);
        }
      }
    }
  }
}

// ---------------- down grouped GEMM, scatter-add into out ----------------
__global__ __launch_bounds__(256, 2) void down_kernel(
    const unsigned short* __restrict__ h_buf, const unsigned short* __restrict__ wd,
    const int* __restrict__ counts, const int* __restrict__ offsets,
    const int* __restrict__ tok_list, const float* __restrict__ tok_w,
    float* __restrict__ out) {
  int nt = blockIdx.x;  // 16: out-col tile of 128
  int mt = blockIdx.y;  // 32
  int e  = blockIdx.z;  // 8
  int count = counts[e];
  if (mt * 128 >= count) return;

  __shared__ unsigned short As[2][128 * 32];
  __shared__ unsigned short Bs[2][128 * 32];

  int tid  = threadIdx.x;
  int lane = tid & 63;
  int wm = (tid >> 7) & 1;
  int wn = (tid >> 6) & 1;

  int row0 = tid >> 2, row1 = row0 + 64;
  int col8 = (((tid & 3) ^ ((tid >> 3) & 3)) * 8);
  int hoff = offsets[e];

  const unsigned short* ag0 =
      h_buf + (size_t)(hoff + imin(mt * 128 + row0, count - 1)) * INTER + col8;
  const unsigned short* ag1 =
      h_buf + (size_t)(hoff + imin(mt * 128 + row1, count - 1)) * INTER + col8;
  const unsigned short* bbase = wd + (size_t)e * HIDDEN * INTER;
  const unsigned short* bg0 = bbase + (size_t)(nt * 128 + row0) * INTER + col8;
  const unsigned short* bg1 = bbase + (size_t)(nt * 128 + row1) * INTER + col8;

  v4f acc[4][4];
#pragma unroll
  for (int i = 0; i < 4; i++)
#pragma unroll
    for (int j = 0; j < 4; j++) acc[i][j] = v4f{0.f, 0.f, 0.f, 0.f};

  int mrow = wm * 64 + (lane & 15);
  int nrow = wn * 64 + (lane & 15);
  int kcol = (((lane >> 4) ^ ((lane >> 1) & 3)) * 8);

  // prologue: stage tile 0 into buf 0
  gld_lds16(ag0, &As[0][(size_t)tid * 8]);
  gld_lds16(ag1, &As[0][2048 + (size_t)tid * 8]);
  gld_lds16(bg0, &Bs[0][(size_t)tid * 8]);
  gld_lds16(bg1, &Bs[0][2048 + (size_t)tid * 8]);
  ag0 += 32; ag1 += 32; bg0 += 32; bg1 += 32;
  __syncthreads();

  const int NK = INTER / 32;
  for (int kt = 0; kt < NK; kt++) {
    int cur = kt & 1;
    if (kt + 1 < NK) {
      int nxt = cur ^ 1;
      gld_lds16(ag0, &As[nxt][(size_t)tid * 8]);
      gld_lds16(ag1, &As[nxt][2048 + (size_t)tid * 8]);
      gld_lds16(bg0, &Bs[nxt][(size_t)tid * 8]);
      gld_lds16(bg1, &Bs[nxt][2048 + (size_t)tid * 8]);
      ag0 += 32; ag1 += 32; bg0 += 32; bg1 += 32;
    }
    v8s a[4], b[4];
#pragma unroll
    for (int i = 0; i < 4; i++) a[i] = *(const v8s*)&As[cur][(mrow + i * 16) * 32 + kcol];
#pragma unroll
    for (int j = 0; j < 4; j++) b[j] = *(const v8s*)&Bs[cur][(nrow + j * 16) * 32 + kcol];
#pragma unroll
    for (int i = 0; i < 4; i++)
#pragma unroll
      for (int j = 0; j < 4; j++)
        acc[i][j] = __builtin_amdgcn_mfma_f32_16x16x32_bf16(a[i], b[j], acc[i][j], 0, 0, 0);
    __syncthreads();
  }

  int ocol  = lane & 15;
  int orow4 = (lane >> 4) * 4;
#pragma unroll
  for (int i = 0; i < 4; i++) {
#pragma unroll
    for (int r = 0; r < 4; r++) {
      int m = mt * 128 + wm * 64 + i * 16 + orow4 + r;
      if (m < count) {
        int tok  = tok_list[e * N_TOKENS + m];
        float w  = tok_w[e * N_TOKENS + m];
        float* orow = out + (size_t)tok * HIDDEN + nt * 128 + wn * 64 + ocol;
#pragma unroll
        for (int j = 0; j < 4; j++) atomicAdd(orow + j * 16, acc[i][j][r] * w);
      }
    }
  }
}

extern "C" void kernel_launch(void* const* d_in, const int* in_sizes, int n_in,
                              void* d_out, int out_size, void* d_ws, size_t ws_size,
                              hipStream_t stream) {
  const float* x   = (const float*)d_in[0];
  const float* rw  = (const float*)d_in[1];
  const float* cb  = (const float*)d_in[2];
  const float* wgu = (const float*)d_in[3];
  const float* wd  = (const float*)d_in[4];
  float* out = (float*)d_out;

  char* ws = (char*)d_ws;
  size_t off = 0;
  auto alloc = [&](size_t bytes) {
    void* p = ws + off;
    off += (bytes + 255) & ~(size_t)255;
    return p;
  };
  unsigned short* xb    = (unsigned short*)alloc((size_t)N_TOKENS * HIDDEN * 2);
  unsigned short* wgu_b = (unsigned short*)alloc((size_t)NE * 2 * INTER * HIDDEN * 2);
  unsigned short* wd_b  = (unsigned short*)alloc((size_t)NE * HIDDEN * INTER * 2);
  unsigned short* h_buf = (unsigned short*)alloc((size_t)2 * N_TOKENS * INTER * 2);
  int*   tok_list = (int*)alloc((size_t)NE * N_TOKENS * 4);
  float* tok_w    = (float*)alloc((size_t)NE * N_TOKENS * 4);
  int*   counts   = (int*)alloc(256);
  int*   offsets  = (int*)alloc(256);
  (void)ws_size; (void)in_sizes; (void)n_in; (void)out_size;

  init_kernel<<<1, 64, 0, stream>>>(counts);
  cvt_kernel<<<(NE * 2 * INTER * HIDDEN / 8 + 255) / 256, 256, 0, stream>>>(
      wgu, wgu_b, NE * 2 * INTER * HIDDEN / 8);
  cvt_kernel<<<(NE * HIDDEN * INTER / 8 + 255) / 256, 256, 0, stream>>>(
      wd, wd_b, NE * HIDDEN * INTER / 8);
  router_kernel<<<N_TOKENS / 4, 256, 0, stream>>>(x, rw, cb, xb, counts, tok_list, tok_w, out);
  offsets_kernel<<<1, 64, 0, stream>>>(counts, offsets);
  gateup_kernel<<<dim3(16, 32, 8), 256, 0, stream>>>(xb, wgu_b, counts, offsets, tok_list, h_buf);
  down_kernel<<<dim3(16, 32, 8), 256, 0, stream>>>(h_buf, wd_b, counts, offsets, tok_list, tok_w, out);
}

// Round 5
// 516.699 us; speedup vs baseline: 1.0631x; 1.0128x over previous
//
#include <hip/hip_runtime.h>
#include <cstdint>
#include <cstddef>

#define N_TOKENS 4096
#define HIDDEN   2048
#define INTER    1024
#define NE       8
#define NE_TOT   10
#define SCALE    2.5f

typedef short v8s __attribute__((ext_vector_type(8)));
typedef float v4f __attribute__((ext_vector_type(4)));

static __device__ inline int imin(int a, int b) { return a < b ? a : b; }

__device__ inline unsigned short f2bf(float f) {
  unsigned int u = __float_as_uint(f);
  u += 0x7fffu + ((u >> 16) & 1u);   // round-to-nearest-even
  return (unsigned short)(u >> 16);
}

__device__ inline void gld_lds16(const void* g, void* l) {
  __builtin_amdgcn_global_load_lds(
      (const __attribute__((address_space(1))) unsigned int*)g,
      (__attribute__((address_space(3))) unsigned int*)l, 16, 0, 0);
}

// ---------------- merged f32->bf16 weight conversion + counts init ----------------
__global__ __launch_bounds__(256) void cvt_all_kernel(
    const float* __restrict__ wgu, const float* __restrict__ wd,
    unsigned short* __restrict__ wgu_b, unsigned short* __restrict__ wd_b,
    int* __restrict__ counts) {
  if (blockIdx.x == 0 && threadIdx.x < NE) counts[threadIdx.x] = 0;
  int i = blockIdx.x * 256 + threadIdx.x;
  const int n8_gu = NE * 2 * INTER * HIDDEN / 8;
  const int n8_d  = NE * HIDDEN * INTER / 8;
  const float* src;
  unsigned short* dst;
  size_t b;
  if (i < n8_gu)            { src = wgu; dst = wgu_b; b = (size_t)i * 8; }
  else if (i < n8_gu + n8_d){ src = wd;  dst = wd_b;  b = (size_t)(i - n8_gu) * 8; }
  else return;
  float4 a0 = *(const float4*)(src + b);
  float4 a1 = *(const float4*)(src + b + 4);
  union { unsigned short u[8]; uint4 v; } r;
  r.u[0] = f2bf(a0.x); r.u[1] = f2bf(a0.y); r.u[2] = f2bf(a0.z); r.u[3] = f2bf(a0.w);
  r.u[4] = f2bf(a1.x); r.u[5] = f2bf(a1.y); r.u[6] = f2bf(a1.z); r.u[7] = f2bf(a1.w);
  *(uint4*)(dst + b) = r.v;
}

// ---------------- router: two-pass low-VGPR; also records per-token (e,slot,w) ----
__global__ __launch_bounds__(256, 4) void router_kernel(
    const float* __restrict__ x, const float* __restrict__ rw,
    const float* __restrict__ bias, unsigned short* __restrict__ xb,
    int* __restrict__ counts, int* __restrict__ tok_list,
    int* __restrict__ tkp, float* __restrict__ tkw, float* __restrict__ out) {
  int tid  = threadIdx.x;
  int lane = tid & 63;
  int wid  = tid >> 6;
  int n    = blockIdx.x * 4 + wid;

  const float* xr = x + (size_t)n * HIDDEN;
  float acc[NE_TOT];
#pragma unroll
  for (int e = 0; e < NE_TOT; e++) acc[e] = 0.f;

#pragma unroll 1
  for (int i = 0; i < 8; i++) {
    int k = (i * 64 + lane) * 4;
    float4 xv = *(const float4*)(xr + k);
#pragma unroll
    for (int e = 0; e < NE_TOT; e++) {
      float4 w = *(const float4*)(rw + (size_t)e * HIDDEN + k);
      acc[e] += xv.x * w.x + xv.y * w.y + xv.z * w.z + xv.w * w.w;
    }
  }
#pragma unroll
  for (int e = 0; e < NE_TOT; e++) {
    float v = acc[e];
#pragma unroll
    for (int off = 32; off > 0; off >>= 1) v += __shfl_xor(v, off, 64);
    acc[e] = v;  // all lanes hold the full dot product
  }

  // sigmoid + bias, top-2 (ties -> lower index), redundantly on all lanes
  float sc[NE_TOT], sb[NE_TOT];
#pragma unroll
  for (int e = 0; e < NE_TOT; e++) {
    sc[e] = 1.f / (1.f + expf(-acc[e]));
    sb[e] = sc[e] + bias[e];
  }
  int i1 = 0;
  for (int e = 1; e < NE_TOT; e++) if (sb[e] > sb[i1]) i1 = e;
  int i2 = (i1 == 0) ? 1 : 0;
  for (int e = 0; e < NE_TOT; e++) if (e != i1 && sb[e] > sb[i2]) i2 = e;
  float wzero = 0.f;
  if (i1 >= NE) wzero += sc[i1];
  if (i2 >= NE) wzero += sc[i2];
  if (lane == 0) {
#pragma unroll
    for (int tt = 0; tt < 2; tt++) {
      int idx = tt == 0 ? i1 : i2;
      int packed = 0;
      float w = 0.f;
      if (idx < NE) {
        int slot = atomicAdd(&counts[idx], 1);
        tok_list[idx * N_TOKENS + slot] = n;
        packed = (idx << 16) | slot;
        w = SCALE * sc[idx];
      }
      tkp[tt * N_TOKENS + n] = packed;   // zero-expert pick -> row 0, w = 0
      tkw[tt * N_TOKENS + n] = w;
    }
  }
  float wz = SCALE * wzero;

  // pass 2: re-read x row (cache-hot), emit xb (bf16) and out = wz*x
#pragma unroll
  for (int i = 0; i < 8; i++) {
    int k = (i * 64 + lane) * 4;
    float4 xv = *(const float4*)(xr + k);
    ushort4 ob;
    ob.x = f2bf(xv.x); ob.y = f2bf(xv.y);
    ob.z = f2bf(xv.z); ob.w = f2bf(xv.w);
    *(ushort4*)(xb + (size_t)n * HIDDEN + k) = ob;
    float4 o;
    o.x = wz * xv.x; o.y = wz * xv.y; o.z = wz * xv.z; o.w = wz * xv.w;
    *(float4*)(out + (size_t)n * HIDDEN + k) = o;
  }
}

// ---------------- prefix offsets over counts ----------------
__global__ void offsets_kernel(const int* __restrict__ counts, int* __restrict__ offsets) {
  if (threadIdx.x == 0) {
    int s = 0;
    for (int e = 0; e < NE; e++) { offsets[e] = s; s += counts[e]; }
  }
}

// LDS xor-swizzle (kills 8-way ds_read_b128 bank conflicts):
// physical 16B chunk p of row r holds logical chunk p ^ ((r>>1)&3).
// Staging (lane tid -> row tid>>2, slot tid&3): fetch global chunk
// (tid&3) ^ ((tid>>3)&3). Readers: physical chunk (lane>>4) ^ ((lane>>1)&3).

// ---------------- gate_up grouped GEMM + fused SiLU*up ----------------
__global__ __launch_bounds__(256, 2) void gateup_kernel(
    const unsigned short* __restrict__ xb, const unsigned short* __restrict__ wgu,
    const int* __restrict__ counts, const int* __restrict__ offsets,
    const int* __restrict__ tok_list, unsigned short* __restrict__ h_buf) {
  int jt = blockIdx.x;  // 16: f-block of 64
  int mt = blockIdx.y;  // 32: token tile of 128
  int e  = blockIdx.z;  // 8
  int count = counts[e];
  if (mt * 128 >= count) return;

  __shared__ unsigned short As[2][128 * 32];
  __shared__ unsigned short Bs[2][128 * 32];

  int tid  = threadIdx.x;
  int lane = tid & 63;
  int wm = (tid >> 7) & 1;
  int wn = (tid >> 6) & 1;

  int row0 = tid >> 2, row1 = row0 + 64;
  int col8 = (((tid & 3) ^ ((tid >> 3) & 3)) * 8);  // swizzled source chunk

  const int* tl = tok_list + e * N_TOKENS;
  int t0 = tl[imin(mt * 128 + row0, count - 1)];
  int t1 = tl[imin(mt * 128 + row1, count - 1)];
  const unsigned short* ag0 = xb + (size_t)t0 * HIDDEN + col8;
  const unsigned short* ag1 = xb + (size_t)t1 * HIDDEN + col8;

  int wn0 = row0 >> 6, wi0 = row0 & 63;
  int wn1 = row1 >> 6, wi1 = row1 & 63;
  int br0 = (wi0 < 32) ? (jt * 64 + wn0 * 32 + wi0) : (1024 + jt * 64 + wn0 * 32 + (wi0 - 32));
  int br1 = (wi1 < 32) ? (jt * 64 + wn1 * 32 + wi1) : (1024 + jt * 64 + wn1 * 32 + (wi1 - 32));
  const unsigned short* bbase = wgu + (size_t)e * (2 * INTER) * HIDDEN;
  const unsigned short* bg0 = bbase + (size_t)br0 * HIDDEN + col8;
  const unsigned short* bg1 = bbase + (size_t)br1 * HIDDEN + col8;

  v4f acc[4][4];
#pragma unroll
  for (int i = 0; i < 4; i++)
#pragma unroll
    for (int j = 0; j < 4; j++) acc[i][j] = v4f{0.f, 0.f, 0.f, 0.f};

  int mrow = wm * 64 + (lane & 15);
  int nrow = wn * 64 + (lane & 15);
  int kcol = (((lane >> 4) ^ ((lane >> 1) & 3)) * 8);  // swizzled read chunk

  // prologue: stage tile 0 into buf 0
  gld_lds16(ag0, &As[0][(size_t)tid * 8]);
  gld_lds16(ag1, &As[0][2048 + (size_t)tid * 8]);
  gld_lds16(bg0, &Bs[0][(size_t)tid * 8]);
  gld_lds16(bg1, &Bs[0][2048 + (size_t)tid * 8]);
  ag0 += 32; ag1 += 32; bg0 += 32; bg1 += 32;
  __syncthreads();

  const int NK = HIDDEN / 32;
  for (int kt = 0; kt < NK; kt++) {
    int cur = kt & 1;
    if (kt + 1 < NK) {
      int nxt = cur ^ 1;
      gld_lds16(ag0, &As[nxt][(size_t)tid * 8]);
      gld_lds16(ag1, &As[nxt][2048 + (size_t)tid * 8]);
      gld_lds16(bg0, &Bs[nxt][(size_t)tid * 8]);
      gld_lds16(bg1, &Bs[nxt][2048 + (size_t)tid * 8]);
      ag0 += 32; ag1 += 32; bg0 += 32; bg1 += 32;
    }
    v8s a[4], b[4];
#pragma unroll
    for (int i = 0; i < 4; i++) a[i] = *(const v8s*)&As[cur][(mrow + i * 16) * 32 + kcol];
#pragma unroll
    for (int j = 0; j < 4; j++) b[j] = *(const v8s*)&Bs[cur][(nrow + j * 16) * 32 + kcol];
#pragma unroll
    for (int i = 0; i < 4; i++)
#pragma unroll
      for (int j = 0; j < 4; j++)
        acc[i][j] = __builtin_amdgcn_mfma_f32_16x16x32_bf16(a[i], b[j], acc[i][j], 0, 0, 0);
    __syncthreads();
  }

  int ocol  = lane & 15;
  int orow4 = (lane >> 4) * 4;
  int hoff  = offsets[e];
#pragma unroll
  for (int i = 0; i < 4; i++) {
#pragma unroll
    for (int r = 0; r < 4; r++) {
      int m = mt * 128 + wm * 64 + i * 16 + orow4 + r;
      if (m < count) {
        unsigned short* hrow = h_buf + (size_t)(hoff + m) * INTER;
#pragma unroll
        for (int j = 0; j < 2; j++) {
          float g = acc[i][j][r];
          float u = acc[i][j + 2][r];
          float hv = (g / (1.f + expf(-g))) * u;
          hrow[jt * 64 + wn * 32 + j * 16 + ocol] = f2bf(hv);
        }
      }
    }
  }
}

// ---------------- down grouped GEMM: plain f32 stores into y_buf (no atomics) ----
__global__ __launch_bounds__(256, 2) void down_kernel(
    const unsigned short* __restrict__ h_buf, const unsigned short* __restrict__ wd,
    const int* __restrict__ counts, const int* __restrict__ offsets,
    float* __restrict__ y_buf) {
  int nt = blockIdx.x;  // 16: out-col tile of 128
  int mt = blockIdx.y;  // 32
  int e  = blockIdx.z;  // 8
  int count = counts[e];
  if (mt * 128 >= count) return;

  __shared__ unsigned short As[2][128 * 32];
  __shared__ unsigned short Bs[2][128 * 32];

  int tid  = threadIdx.x;
  int lane = tid & 63;
  int wm = (tid >> 7) & 1;
  int wn = (tid >> 6) & 1;

  int row0 = tid >> 2, row1 = row0 + 64;
  int col8 = (((tid & 3) ^ ((tid >> 3) & 3)) * 8);
  int hoff = offsets[e];

  const unsigned short* ag0 =
      h_buf + (size_t)(hoff + imin(mt * 128 + row0, count - 1)) * INTER + col8;
  const unsigned short* ag1 =
      h_buf + (size_t)(hoff + imin(mt * 128 + row1, count - 1)) * INTER + col8;
  const unsigned short* bbase = wd + (size_t)e * HIDDEN * INTER;
  const unsigned short* bg0 = bbase + (size_t)(nt * 128 + row0) * INTER + col8;
  const unsigned short* bg1 = bbase + (size_t)(nt * 128 + row1) * INTER + col8;

  v4f acc[4][4];
#pragma unroll
  for (int i = 0; i < 4; i++)
#pragma unroll
    for (int j = 0; j < 4; j++) acc[i][j] = v4f{0.f, 0.f, 0.f, 0.f};

  int mrow = wm * 64 + (lane & 15);
  int nrow = wn * 64 + (lane & 15);
  int kcol = (((lane >> 4) ^ ((lane >> 1) & 3)) * 8);

  // prologue: stage tile 0 into buf 0
  gld_lds16(ag0, &As[0][(size_t)tid * 8]);
  gld_lds16(ag1, &As[0][2048 + (size_t)tid * 8]);
  gld_lds16(bg0, &Bs[0][(size_t)tid * 8]);
  gld_lds16(bg1, &Bs[0][2048 + (size_t)tid * 8]);
  ag0 += 32; ag1 += 32; bg0 += 32; bg1 += 32;
  __syncthreads();

  const int NK = INTER / 32;
  for (int kt = 0; kt < NK; kt++) {
    int cur = kt & 1;
    if (kt + 1 < NK) {
      int nxt = cur ^ 1;
      gld_lds16(ag0, &As[nxt][(size_t)tid * 8]);
      gld_lds16(ag1, &As[nxt][2048 + (size_t)tid * 8]);
      gld_lds16(bg0, &Bs[nxt][(size_t)tid * 8]);
      gld_lds16(bg1, &Bs[nxt][2048 + (size_t)tid * 8]);
      ag0 += 32; ag1 += 32; bg0 += 32; bg1 += 32;
    }
    v8s a[4], b[4];
#pragma unroll
    for (int i = 0; i < 4; i++) a[i] = *(const v8s*)&As[cur][(mrow + i * 16) * 32 + kcol];
#pragma unroll
    for (int j = 0; j < 4; j++) b[j] = *(const v8s*)&Bs[cur][(nrow + j * 16) * 32 + kcol];
#pragma unroll
    for (int i = 0; i < 4; i++)
#pragma unroll
      for (int j = 0; j < 4; j++)
        acc[i][j] = __builtin_amdgcn_mfma_f32_16x16x32_bf16(a[i], b[j], acc[i][j], 0, 0, 0);
    __syncthreads();
  }

  int ocol  = lane & 15;
  int orow4 = (lane >> 4) * 4;
#pragma unroll
  for (int i = 0; i < 4; i++) {
#pragma unroll
    for (int r = 0; r < 4; r++) {
      int m = mt * 128 + wm * 64 + i * 16 + orow4 + r;
      if (m < count) {
        float* yrow = y_buf + (size_t)(hoff + m) * HIDDEN + nt * 128 + wn * 64 + ocol;
#pragma unroll
        for (int j = 0; j < 4; j++) yrow[j * 16] = acc[i][j][r];
      }
    }
  }
}

// ---------------- gather: out += w1*y[row1] + w2*y[row2], one token per wave ----
__global__ __launch_bounds__(256, 4) void gather_kernel(
    const float* __restrict__ y_buf, const int* __restrict__ tkp,
    const float* __restrict__ tkw, const int* __restrict__ offsets,
    float* __restrict__ out) {
  int tid  = threadIdx.x;
  int lane = tid & 63;
  int wid  = tid >> 6;
  int n    = blockIdx.x * 4 + wid;

  int p1 = tkp[n], p2 = tkp[N_TOKENS + n];
  float w1 = tkw[n], w2 = tkw[N_TOKENS + n];
  const float* y1 = y_buf + (size_t)(offsets[p1 >> 16] + (p1 & 0xffff)) * HIDDEN;
  const float* y2 = y_buf + (size_t)(offsets[p2 >> 16] + (p2 & 0xffff)) * HIDDEN;
  float* orow = out + (size_t)n * HIDDEN;

#pragma unroll
  for (int i = 0; i < 8; i++) {
    int k = (i * 64 + lane) * 4;
    float4 o = *(const float4*)(orow + k);
    float4 a = *(const float4*)(y1 + k);
    float4 b = *(const float4*)(y2 + k);
    o.x += w1 * a.x + w2 * b.x;
    o.y += w1 * a.y + w2 * b.y;
    o.z += w1 * a.z + w2 * b.z;
    o.w += w1 * a.w + w2 * b.w;
    *(float4*)(orow + k) = o;
  }
}

extern "C" void kernel_launch(void* const* d_in, const int* in_sizes, int n_in,
                              void* d_out, int out_size, void* d_ws, size_t ws_size,
                              hipStream_t stream) {
  const float* x   = (const float*)d_in[0];
  const float* rw  = (const float*)d_in[1];
  const float* cb  = (const float*)d_in[2];
  const float* wgu = (const float*)d_in[3];
  const float* wd  = (const float*)d_in[4];
  float* out = (float*)d_out;

  char* ws = (char*)d_ws;
  size_t off = 0;
  auto alloc = [&](size_t bytes) {
    void* p = ws + off;
    off += (bytes + 255) & ~(size_t)255;
    return p;
  };
  unsigned short* xb    = (unsigned short*)alloc((size_t)N_TOKENS * HIDDEN * 2);
  unsigned short* wgu_b = (unsigned short*)alloc((size_t)NE * 2 * INTER * HIDDEN * 2);
  unsigned short* wd_b  = (unsigned short*)alloc((size_t)NE * HIDDEN * INTER * 2);
  unsigned short* h_buf = (unsigned short*)alloc((size_t)2 * N_TOKENS * INTER * 2);
  int*   tok_list = (int*)alloc((size_t)NE * N_TOKENS * 4);
  int*   tkp      = (int*)alloc((size_t)2 * N_TOKENS * 4);
  float* tkw      = (float*)alloc((size_t)2 * N_TOKENS * 4);
  int*   counts   = (int*)alloc(256);
  int*   offsets  = (int*)alloc(256);
  // y_buf (8192 x 2048 f32 = 64 MiB) aliases wgu_b (same size): wgu_b is dead
  // after gateup_kernel; down writes y there, gather reads it, next iteration's
  // cvt rewrites it. Stream-ordered, safe.
  float* y_buf = (float*)wgu_b;
  (void)ws_size; (void)in_sizes; (void)n_in; (void)out_size;

  const int n8_total = (NE * 2 * INTER * HIDDEN + NE * HIDDEN * INTER) / 8;
  cvt_all_kernel<<<(n8_total + 255) / 256, 256, 0, stream>>>(wgu, wd, wgu_b, wd_b, counts);
  router_kernel<<<N_TOKENS / 4, 256, 0, stream>>>(x, rw, cb, xb, counts, tok_list, tkp, tkw, out);
  offsets_kernel<<<1, 64, 0, stream>>>(counts, offsets);
  gateup_kernel<<<dim3(16, 32, 8), 256, 0, stream>>>(xb, wgu_b, counts, offsets, tok_list, h_buf);
  down_kernel<<<dim3(16, 32, 8), 256, 0, stream>>>(h_buf, wd_b, counts, offsets, y_buf);
  gather_kernel<<<N_TOKENS / 4, 256, 0, stream>>>(y_buf, tkp, tkw, offsets, out);
}

// Round 6
// 459.772 us; speedup vs baseline: 1.1948x; 1.1238x over previous
//
#include <hip/hip_runtime.h>
#include <cstdint>
#include <cstddef>

#define N_TOKENS 4096
#define HIDDEN   2048
#define INTER    1024
#define NE       8
#define NE_TOT   10
#define SCALE    2.5f

typedef short v8s __attribute__((ext_vector_type(8)));
typedef float v4f __attribute__((ext_vector_type(4)));

static __device__ inline int imin(int a, int b) { return a < b ? a : b; }

__device__ inline unsigned short f2bf(float f) {
  unsigned int u = __float_as_uint(f);
  u += 0x7fffu + ((u >> 16) & 1u);   // round-to-nearest-even
  return (unsigned short)(u >> 16);
}

__device__ inline void gld_lds16(const void* g, void* l) {
  __builtin_amdgcn_global_load_lds(
      (const __attribute__((address_space(1))) unsigned int*)g,
      (__attribute__((address_space(3))) unsigned int*)l, 16, 0, 0);
}

// ---------------- merged f32->bf16 weight conversion ----------------
__global__ __launch_bounds__(256) void cvt_all_kernel(
    const float* __restrict__ wgu, const float* __restrict__ wd,
    unsigned short* __restrict__ wgu_b, unsigned short* __restrict__ wd_b) {
  int i = blockIdx.x * 256 + threadIdx.x;
  const int n8_gu = NE * 2 * INTER * HIDDEN / 8;
  const int n8_d  = NE * HIDDEN * INTER / 8;
  const float* src;
  unsigned short* dst;
  size_t b;
  if (i < n8_gu)            { src = wgu; dst = wgu_b; b = (size_t)i * 8; }
  else if (i < n8_gu + n8_d){ src = wd;  dst = wd_b;  b = (size_t)(i - n8_gu) * 8; }
  else return;
  float4 a0 = *(const float4*)(src + b);
  float4 a1 = *(const float4*)(src + b + 4);
  union { unsigned short u[8]; uint4 v; } r;
  r.u[0] = f2bf(a0.x); r.u[1] = f2bf(a0.y); r.u[2] = f2bf(a0.z); r.u[3] = f2bf(a0.w);
  r.u[4] = f2bf(a1.x); r.u[5] = f2bf(a1.y); r.u[6] = f2bf(a1.z); r.u[7] = f2bf(a1.w);
  *(uint4*)(dst + b) = r.v;
}

// ---------------- router: ATOMIC-FREE. Writes per-token expert ids + weights ----
// R0/R1/R5 routers all cost ~101-106 us regardless of structure: the invariant
// was 8192 device-scope atomicAdds onto one 32B counts[] line (~12 ns/RMW
// serialized at the cross-XCD coherence point). Slot assignment moved to
// partition_kernel; this kernel now has zero atomics.
__global__ __launch_bounds__(256, 4) void router_kernel(
    const float* __restrict__ x, const float* __restrict__ rw,
    const float* __restrict__ bias, unsigned short* __restrict__ xb,
    signed char* __restrict__ tke, float* __restrict__ tkw,
    float* __restrict__ out) {
  int tid  = threadIdx.x;
  int lane = tid & 63;
  int wid  = tid >> 6;
  int n    = blockIdx.x * 4 + wid;

  const float* xr = x + (size_t)n * HIDDEN;
  float acc[NE_TOT];
#pragma unroll
  for (int e = 0; e < NE_TOT; e++) acc[e] = 0.f;

#pragma unroll 1
  for (int i = 0; i < 8; i++) {
    int k = (i * 64 + lane) * 4;
    float4 xv = *(const float4*)(xr + k);
#pragma unroll
    for (int e = 0; e < NE_TOT; e++) {
      float4 w = *(const float4*)(rw + (size_t)e * HIDDEN + k);
      acc[e] += xv.x * w.x + xv.y * w.y + xv.z * w.z + xv.w * w.w;
    }
  }
#pragma unroll
  for (int e = 0; e < NE_TOT; e++) {
    float v = acc[e];
#pragma unroll
    for (int off = 32; off > 0; off >>= 1) v += __shfl_xor(v, off, 64);
    acc[e] = v;  // all lanes hold the full dot product
  }

  // sigmoid + bias, top-2 (ties -> lower index), redundantly on all lanes
  float sc[NE_TOT], sb[NE_TOT];
#pragma unroll
  for (int e = 0; e < NE_TOT; e++) {
    sc[e] = 1.f / (1.f + expf(-acc[e]));
    sb[e] = sc[e] + bias[e];
  }
  int i1 = 0;
  for (int e = 1; e < NE_TOT; e++) if (sb[e] > sb[i1]) i1 = e;
  int i2 = (i1 == 0) ? 1 : 0;
  for (int e = 0; e < NE_TOT; e++) if (e != i1 && sb[e] > sb[i2]) i2 = e;
  float wzero = 0.f;
  if (i1 >= NE) wzero += sc[i1];
  if (i2 >= NE) wzero += sc[i2];
  if (lane == 0) {
    tke[n]            = (signed char)(i1 < NE ? i1 : -1);
    tke[N_TOKENS + n] = (signed char)(i2 < NE ? i2 : -1);
    tkw[n]            = i1 < NE ? SCALE * sc[i1] : 0.f;
    tkw[N_TOKENS + n] = i2 < NE ? SCALE * sc[i2] : 0.f;
  }
  float wz = SCALE * wzero;

  // pass 2: re-read x row (cache-hot), emit xb (bf16) and out = wz*x
#pragma unroll
  for (int i = 0; i < 8; i++) {
    int k = (i * 64 + lane) * 4;
    float4 xv = *(const float4*)(xr + k);
    ushort4 ob;
    ob.x = f2bf(xv.x); ob.y = f2bf(xv.y);
    ob.z = f2bf(xv.z); ob.w = f2bf(xv.w);
    *(ushort4*)(xb + (size_t)n * HIDDEN + k) = ob;
    float4 o;
    o.x = wz * xv.x; o.y = wz * xv.y; o.z = wz * xv.z; o.w = wz * xv.w;
    *(float4*)(out + (size_t)n * HIDDEN + k) = o;
  }
}

// ---------------- partition: deterministic slot assignment, no atomics ----------
// Single block, 1024 threads; each thread owns 4 tokens (8 pick entries).
// Per-thread expert counts in own LDS row -> Hillis-Steele scan over 1024
// threads (8 experts in parallel) -> counts/offsets -> re-walk entries
// assigning slots; emits tok_list and resolved y-row per pick (tkr).
__global__ __launch_bounds__(1024) void partition_kernel(
    const signed char* __restrict__ tke, int* __restrict__ tok_list,
    int* __restrict__ tkr, int* __restrict__ counts, int* __restrict__ offsets) {
  __shared__ int scn[1024][NE];   // 32 KB
  __shared__ int soff[NE];
  int tid = threadIdx.x;
  int t4  = tid * 4;

  int w0 = *(const int*)(tke + t4);             // picks tt=0, tokens t4..t4+3
  int w1 = *(const int*)(tke + N_TOKENS + t4);  // picks tt=1

#pragma unroll
  for (int e = 0; e < NE; e++) scn[tid][e] = 0;
#pragma unroll
  for (int i = 0; i < 4; i++) {
    int e0 = (int)(signed char)(w0 >> (8 * i));
    int e1 = (int)(signed char)(w1 >> (8 * i));
    if (e0 >= 0) scn[tid][e0]++;
    if (e1 >= 0) scn[tid][e1]++;
  }
  int c[NE], orig[NE];
#pragma unroll
  for (int e = 0; e < NE; e++) { c[e] = scn[tid][e]; orig[e] = c[e]; }
  __syncthreads();

  for (int s = 1; s < 1024; s <<= 1) {
    int v[NE];
    bool act = (tid >= s);
    if (act) {
#pragma unroll
      for (int e = 0; e < NE; e++) v[e] = scn[tid - s][e];
    }
    __syncthreads();
    if (act) {
#pragma unroll
      for (int e = 0; e < NE; e++) { c[e] += v[e]; scn[tid][e] = c[e]; }
    }
    __syncthreads();
  }

  if (tid == 0) {
    int s = 0;
#pragma unroll
    for (int e = 0; e < NE; e++) {
      int cnt = scn[1023][e];
      counts[e] = cnt; offsets[e] = s; soff[e] = s; s += cnt;
    }
  }
  __syncthreads();

  // own-row cursors: within-expert exclusive prefix for this thread
#pragma unroll
  for (int e = 0; e < NE; e++) scn[tid][e] = c[e] - orig[e];

#pragma unroll
  for (int i = 0; i < 4; i++) {
    int n  = t4 + i;
    int e0 = (int)(signed char)(w0 >> (8 * i));
    int e1 = (int)(signed char)(w1 >> (8 * i));
    if (e0 >= 0) {
      int slot = scn[tid][e0]++;
      tok_list[e0 * N_TOKENS + slot] = n;
      tkr[n] = soff[e0] + slot;
    } else tkr[n] = 0;
    if (e1 >= 0) {
      int slot = scn[tid][e1]++;
      tok_list[e1 * N_TOKENS + slot] = n;
      tkr[N_TOKENS + n] = soff[e1] + slot;
    } else tkr[N_TOKENS + n] = 0;
  }
}

// LDS xor-swizzle (kills 8-way ds_read_b128 bank conflicts):
// physical 16B chunk p of row r holds logical chunk p ^ ((r>>1)&3).
// Staging (lane tid -> row tid>>2, slot tid&3): fetch global chunk
// (tid&3) ^ ((tid>>3)&3). Readers: physical chunk (lane>>4) ^ ((lane>>1)&3).

// ---------------- gate_up grouped GEMM + fused SiLU*up ----------------
__global__ __launch_bounds__(256, 2) void gateup_kernel(
    const unsigned short* __restrict__ xb, const unsigned short* __restrict__ wgu,
    const int* __restrict__ counts, const int* __restrict__ offsets,
    const int* __restrict__ tok_list, unsigned short* __restrict__ h_buf) {
  int jt = blockIdx.x;  // 16: f-block of 64
  int mt = blockIdx.y;  // 32: token tile of 128
  int e  = blockIdx.z;  // 8
  int count = counts[e];
  if (mt * 128 >= count) return;

  __shared__ unsigned short As[2][128 * 32];
  __shared__ unsigned short Bs[2][128 * 32];

  int tid  = threadIdx.x;
  int lane = tid & 63;
  int wm = (tid >> 7) & 1;
  int wn = (tid >> 6) & 1;

  int row0 = tid >> 2, row1 = row0 + 64;
  int col8 = (((tid & 3) ^ ((tid >> 3) & 3)) * 8);  // swizzled source chunk

  const int* tl = tok_list + e * N_TOKENS;
  int t0 = tl[imin(mt * 128 + row0, count - 1)];
  int t1 = tl[imin(mt * 128 + row1, count - 1)];
  const unsigned short* ag0 = xb + (size_t)t0 * HIDDEN + col8;
  const unsigned short* ag1 = xb + (size_t)t1 * HIDDEN + col8;

  int wn0 = row0 >> 6, wi0 = row0 & 63;
  int wn1 = row1 >> 6, wi1 = row1 & 63;
  int br0 = (wi0 < 32) ? (jt * 64 + wn0 * 32 + wi0) : (1024 + jt * 64 + wn0 * 32 + (wi0 - 32));
  int br1 = (wi1 < 32) ? (jt * 64 + wn1 * 32 + wi1) : (1024 + jt * 64 + wn1 * 32 + (wi1 - 32));
  const unsigned short* bbase = wgu + (size_t)e * (2 * INTER) * HIDDEN;
  const unsigned short* bg0 = bbase + (size_t)br0 * HIDDEN + col8;
  const unsigned short* bg1 = bbase + (size_t)br1 * HIDDEN + col8;

  v4f acc[4][4];
#pragma unroll
  for (int i = 0; i < 4; i++)
#pragma unroll
    for (int j = 0; j < 4; j++) acc[i][j] = v4f{0.f, 0.f, 0.f, 0.f};

  int mrow = wm * 64 + (lane & 15);
  int nrow = wn * 64 + (lane & 15);
  int kcol = (((lane >> 4) ^ ((lane >> 1) & 3)) * 8);  // swizzled read chunk

  // prologue: stage tile 0 into buf 0
  gld_lds16(ag0, &As[0][(size_t)tid * 8]);
  gld_lds16(ag1, &As[0][2048 + (size_t)tid * 8]);
  gld_lds16(bg0, &Bs[0][(size_t)tid * 8]);
  gld_lds16(bg1, &Bs[0][2048 + (size_t)tid * 8]);
  ag0 += 32; ag1 += 32; bg0 += 32; bg1 += 32;
  __syncthreads();

  const int NK = HIDDEN / 32;
  for (int kt = 0; kt < NK; kt++) {
    int cur = kt & 1;
    if (kt + 1 < NK) {
      int nxt = cur ^ 1;
      gld_lds16(ag0, &As[nxt][(size_t)tid * 8]);
      gld_lds16(ag1, &As[nxt][2048 + (size_t)tid * 8]);
      gld_lds16(bg0, &Bs[nxt][(size_t)tid * 8]);
      gld_lds16(bg1, &Bs[nxt][2048 + (size_t)tid * 8]);
      ag0 += 32; ag1 += 32; bg0 += 32; bg1 += 32;
    }
    v8s a[4], b[4];
#pragma unroll
    for (int i = 0; i < 4; i++) a[i] = *(const v8s*)&As[cur][(mrow + i * 16) * 32 + kcol];
#pragma unroll
    for (int j = 0; j < 4; j++) b[j] = *(const v8s*)&Bs[cur][(nrow + j * 16) * 32 + kcol];
#pragma unroll
    for (int i = 0; i < 4; i++)
#pragma unroll
      for (int j = 0; j < 4; j++)
        acc[i][j] = __builtin_amdgcn_mfma_f32_16x16x32_bf16(a[i], b[j], acc[i][j], 0, 0, 0);
    __syncthreads();
  }

  int ocol  = lane & 15;
  int orow4 = (lane >> 4) * 4;
  int hoff  = offsets[e];
#pragma unroll
  for (int i = 0; i < 4; i++) {
#pragma unroll
    for (int r = 0; r < 4; r++) {
      int m = mt * 128 + wm * 64 + i * 16 + orow4 + r;
      if (m < count) {
        unsigned short* hrow = h_buf + (size_t)(hoff + m) * INTER;
#pragma unroll
        for (int j = 0; j < 2; j++) {
          float g = acc[i][j][r];
          float u = acc[i][j + 2][r];
          float hv = (g / (1.f + expf(-g))) * u;
          hrow[jt * 64 + wn * 32 + j * 16 + ocol] = f2bf(hv);
        }
      }
    }
  }
}

// ---------------- down grouped GEMM: plain f32 stores into y_buf (no atomics) ----
__global__ __launch_bounds__(256, 2) void down_kernel(
    const unsigned short* __restrict__ h_buf, const unsigned short* __restrict__ wd,
    const int* __restrict__ counts, const int* __restrict__ offsets,
    float* __restrict__ y_buf) {
  int nt = blockIdx.x;  // 16: out-col tile of 128
  int mt = blockIdx.y;  // 32
  int e  = blockIdx.z;  // 8
  int count = counts[e];
  if (mt * 128 >= count) return;

  __shared__ unsigned short As[2][128 * 32];
  __shared__ unsigned short Bs[2][128 * 32];

  int tid  = threadIdx.x;
  int lane = tid & 63;
  int wm = (tid >> 7) & 1;
  int wn = (tid >> 6) & 1;

  int row0 = tid >> 2, row1 = row0 + 64;
  int col8 = (((tid & 3) ^ ((tid >> 3) & 3)) * 8);
  int hoff = offsets[e];

  const unsigned short* ag0 =
      h_buf + (size_t)(hoff + imin(mt * 128 + row0, count - 1)) * INTER + col8;
  const unsigned short* ag1 =
      h_buf + (size_t)(hoff + imin(mt * 128 + row1, count - 1)) * INTER + col8;
  const unsigned short* bbase = wd + (size_t)e * HIDDEN * INTER;
  const unsigned short* bg0 = bbase + (size_t)(nt * 128 + row0) * INTER + col8;
  const unsigned short* bg1 = bbase + (size_t)(nt * 128 + row1) * INTER + col8;

  v4f acc[4][4];
#pragma unroll
  for (int i = 0; i < 4; i++)
#pragma unroll
    for (int j = 0; j < 4; j++) acc[i][j] = v4f{0.f, 0.f, 0.f, 0.f};

  int mrow = wm * 64 + (lane & 15);
  int nrow = wn * 64 + (lane & 15);
  int kcol = (((lane >> 4) ^ ((lane >> 1) & 3)) * 8);

  // prologue: stage tile 0 into buf 0
  gld_lds16(ag0, &As[0][(size_t)tid * 8]);
  gld_lds16(ag1, &As[0][2048 + (size_t)tid * 8]);
  gld_lds16(bg0, &Bs[0][(size_t)tid * 8]);
  gld_lds16(bg1, &Bs[0][2048 + (size_t)tid * 8]);
  ag0 += 32; ag1 += 32; bg0 += 32; bg1 += 32;
  __syncthreads();

  const int NK = INTER / 32;
  for (int kt = 0; kt < NK; kt++) {
    int cur = kt & 1;
    if (kt + 1 < NK) {
      int nxt = cur ^ 1;
      gld_lds16(ag0, &As[nxt][(size_t)tid * 8]);
      gld_lds16(ag1, &As[nxt][2048 + (size_t)tid * 8]);
      gld_lds16(bg0, &Bs[nxt][(size_t)tid * 8]);
      gld_lds16(bg1, &Bs[nxt][2048 + (size_t)tid * 8]);
      ag0 += 32; ag1 += 32; bg0 += 32; bg1 += 32;
    }
    v8s a[4], b[4];
#pragma unroll
    for (int i = 0; i < 4; i++) a[i] = *(const v8s*)&As[cur][(mrow + i * 16) * 32 + kcol];
#pragma unroll
    for (int j = 0; j < 4; j++) b[j] = *(const v8s*)&Bs[cur][(nrow + j * 16) * 32 + kcol];
#pragma unroll
    for (int i = 0; i < 4; i++)
#pragma unroll
      for (int j = 0; j < 4; j++)
        acc[i][j] = __builtin_amdgcn_mfma_f32_16x16x32_bf16(a[i], b[j], acc[i][j], 0, 0, 0);
    __syncthreads();
  }

  int ocol  = lane & 15;
  int orow4 = (lane >> 4) * 4;
#pragma unroll
  for (int i = 0; i < 4; i++) {
#pragma unroll
    for (int r = 0; r < 4; r++) {
      int m = mt * 128 + wm * 64 + i * 16 + orow4 + r;
      if (m < count) {
        float* yrow = y_buf + (size_t)(hoff + m) * HIDDEN + nt * 128 + wn * 64 + ocol;
#pragma unroll
        for (int j = 0; j < 4; j++) yrow[j * 16] = acc[i][j][r];
      }
    }
  }
}

// ---------------- gather: out += w1*y[r1] + w2*y[r2], one token per wave ----
__global__ __launch_bounds__(256, 4) void gather_kernel(
    const float* __restrict__ y_buf, const int* __restrict__ tkr,
    const float* __restrict__ tkw, float* __restrict__ out) {
  int tid  = threadIdx.x;
  int lane = tid & 63;
  int wid  = tid >> 6;
  int n    = blockIdx.x * 4 + wid;

  int r1 = tkr[n], r2 = tkr[N_TOKENS + n];
  float w1 = tkw[n], w2 = tkw[N_TOKENS + n];
  const float* y1 = y_buf + (size_t)r1 * HIDDEN;
  const float* y2 = y_buf + (size_t)r2 * HIDDEN;
  float* orow = out + (size_t)n * HIDDEN;

#pragma unroll
  for (int i = 0; i < 8; i++) {
    int k = (i * 64 + lane) * 4;
    float4 o = *(const float4*)(orow + k);
    float4 a = *(const float4*)(y1 + k);
    float4 b = *(const float4*)(y2 + k);
    o.x += w1 * a.x + w2 * b.x;
    o.y += w1 * a.y + w2 * b.y;
    o.z += w1 * a.z + w2 * b.z;
    o.w += w1 * a.w + w2 * b.w;
    *(float4*)(orow + k) = o;
  }
}

extern "C" void kernel_launch(void* const* d_in, const int* in_sizes, int n_in,
                              void* d_out, int out_size, void* d_ws, size_t ws_size,
                              hipStream_t stream) {
  const float* x   = (const float*)d_in[0];
  const float* rw  = (const float*)d_in[1];
  const float* cb  = (const float*)d_in[2];
  const float* wgu = (const float*)d_in[3];
  const float* wd  = (const float*)d_in[4];
  float* out = (float*)d_out;

  char* ws = (char*)d_ws;
  size_t off = 0;
  auto alloc = [&](size_t bytes) {
    void* p = ws + off;
    off += (bytes + 255) & ~(size_t)255;
    return p;
  };
  unsigned short* xb    = (unsigned short*)alloc((size_t)N_TOKENS * HIDDEN * 2);
  unsigned short* wgu_b = (unsigned short*)alloc((size_t)NE * 2 * INTER * HIDDEN * 2);
  unsigned short* wd_b  = (unsigned short*)alloc((size_t)NE * HIDDEN * INTER * 2);
  unsigned short* h_buf = (unsigned short*)alloc((size_t)2 * N_TOKENS * INTER * 2);
  int*   tok_list = (int*)alloc((size_t)NE * N_TOKENS * 4);
  signed char* tke = (signed char*)alloc((size_t)2 * N_TOKENS);
  int*   tkr      = (int*)alloc((size_t)2 * N_TOKENS * 4);
  float* tkw      = (float*)alloc((size_t)2 * N_TOKENS * 4);
  int*   counts   = (int*)alloc(256);
  int*   offsets  = (int*)alloc(256);
  // y_buf (8192 x 2048 f32 = 64 MiB) aliases wgu_b (same size): wgu_b is dead
  // after gateup_kernel; down writes y there, gather reads it, next iteration's
  // cvt rewrites it. Stream-ordered, safe.
  float* y_buf = (float*)wgu_b;
  (void)ws_size; (void)in_sizes; (void)n_in; (void)out_size;

  const int n8_total = (NE * 2 * INTER * HIDDEN + NE * HIDDEN * INTER) / 8;
  cvt_all_kernel<<<(n8_total + 255) / 256, 256, 0, stream>>>(wgu, wd, wgu_b, wd_b);
  router_kernel<<<N_TOKENS / 4, 256, 0, stream>>>(x, rw, cb, xb, tke, tkw, out);
  partition_kernel<<<1, 1024, 0, stream>>>(tke, tok_list, tkr, counts, offsets);
  gateup_kernel<<<dim3(16, 32, 8), 256, 0, stream>>>(xb, wgu_b, counts, offsets, tok_list, h_buf);
  down_kernel<<<dim3(16, 32, 8), 256, 0, stream>>>(h_buf, wd_b, counts, offsets, y_buf);
  gather_kernel<<<N_TOKENS / 4, 256, 0, stream>>>(y_buf, tkr, tkw, out);
}

// Round 7
// 448.875 us; speedup vs baseline: 1.2238x; 1.0243x over previous
//
#include <hip/hip_runtime.h>
#include <cstdint>
#include <cstddef>

#define N_TOKENS 4096
#define HIDDEN   2048
#define INTER    1024
#define NE       8
#define NE_TOT   10
#define SCALE    2.5f

typedef short v8s __attribute__((ext_vector_type(8)));
typedef float v4f __attribute__((ext_vector_type(4)));

static __device__ inline int imin(int a, int b) { return a < b ? a : b; }

__device__ inline unsigned short f2bf(float f) {
  unsigned int u = __float_as_uint(f);
  u += 0x7fffu + ((u >> 16) & 1u);   // round-to-nearest-even
  return (unsigned short)(u >> 16);
}

__device__ inline void gld_lds16(const void* g, void* l) {
  __builtin_amdgcn_global_load_lds(
      (const __attribute__((address_space(1))) unsigned int*)g,
      (__attribute__((address_space(3))) unsigned int*)l, 16, 0, 0);
}

#define ROUTER_BLOCKS (N_TOKENS / 4)
#define N8_TOTAL ((NE * 2 * INTER * HIDDEN + NE * HIDDEN * INTER) / 8)
#define CVT_BLOCKS ((N8_TOTAL + 255) / 256)

// ---------------- prep: fused router + weight cvt (independent, one dispatch) ----
// Blocks [0, ROUTER_BLOCKS): router (4 tokens/block, 1/wave).
// Blocks [ROUTER_BLOCKS, ...): f32->bf16 weight conversion.
// Both are BW-bound; fusing runs them at aggregate BW instead of serially.
__global__ __launch_bounds__(256) void prep_kernel(
    const float* __restrict__ x, const float* __restrict__ rw,
    const float* __restrict__ bias, unsigned short* __restrict__ xb,
    signed char* __restrict__ tke, float* __restrict__ tkw,
    float* __restrict__ out,
    const float* __restrict__ wgu, const float* __restrict__ wd,
    unsigned short* __restrict__ wgu_b, unsigned short* __restrict__ wd_b) {
  int tid = threadIdx.x;
  if (blockIdx.x >= ROUTER_BLOCKS) {
    // ---- cvt part ----
    int i = (blockIdx.x - ROUTER_BLOCKS) * 256 + tid;
    const int n8_gu = NE * 2 * INTER * HIDDEN / 8;
    const int n8_d  = NE * HIDDEN * INTER / 8;
    const float* src;
    unsigned short* dst;
    size_t b;
    if (i < n8_gu)             { src = wgu; dst = wgu_b; b = (size_t)i * 8; }
    else if (i < n8_gu + n8_d) { src = wd;  dst = wd_b;  b = (size_t)(i - n8_gu) * 8; }
    else return;
    float4 a0 = *(const float4*)(src + b);
    float4 a1 = *(const float4*)(src + b + 4);
    union { unsigned short u[8]; uint4 v; } r;
    r.u[0] = f2bf(a0.x); r.u[1] = f2bf(a0.y); r.u[2] = f2bf(a0.z); r.u[3] = f2bf(a0.w);
    r.u[4] = f2bf(a1.x); r.u[5] = f2bf(a1.y); r.u[6] = f2bf(a1.z); r.u[7] = f2bf(a1.w);
    *(uint4*)(dst + b) = r.v;
    return;
  }

  // ---- router part (atomic-free; slot assignment in partition_kernel) ----
  int lane = tid & 63;
  int wid  = tid >> 6;
  int n    = blockIdx.x * 4 + wid;

  const float* xr = x + (size_t)n * HIDDEN;
  float acc[NE_TOT];
#pragma unroll
  for (int e = 0; e < NE_TOT; e++) acc[e] = 0.f;

#pragma unroll 1
  for (int i = 0; i < 8; i++) {
    int k = (i * 64 + lane) * 4;
    float4 xv = *(const float4*)(xr + k);
#pragma unroll
    for (int e = 0; e < NE_TOT; e++) {
      float4 w = *(const float4*)(rw + (size_t)e * HIDDEN + k);
      acc[e] += xv.x * w.x + xv.y * w.y + xv.z * w.z + xv.w * w.w;
    }
  }
#pragma unroll
  for (int e = 0; e < NE_TOT; e++) {
    float v = acc[e];
#pragma unroll
    for (int off = 32; off > 0; off >>= 1) v += __shfl_xor(v, off, 64);
    acc[e] = v;  // all lanes hold the full dot product
  }

  // sigmoid + bias, top-2 (ties -> lower index), redundantly on all lanes
  float sc[NE_TOT], sb[NE_TOT];
#pragma unroll
  for (int e = 0; e < NE_TOT; e++) {
    sc[e] = 1.f / (1.f + expf(-acc[e]));
    sb[e] = sc[e] + bias[e];
  }
  int i1 = 0;
  for (int e = 1; e < NE_TOT; e++) if (sb[e] > sb[i1]) i1 = e;
  int i2 = (i1 == 0) ? 1 : 0;
  for (int e = 0; e < NE_TOT; e++) if (e != i1 && sb[e] > sb[i2]) i2 = e;
  float wzero = 0.f;
  if (i1 >= NE) wzero += sc[i1];
  if (i2 >= NE) wzero += sc[i2];
  if (lane == 0) {
    tke[n]            = (signed char)(i1 < NE ? i1 : -1);
    tke[N_TOKENS + n] = (signed char)(i2 < NE ? i2 : -1);
    tkw[n]            = i1 < NE ? SCALE * sc[i1] : 0.f;
    tkw[N_TOKENS + n] = i2 < NE ? SCALE * sc[i2] : 0.f;
  }
  float wz = SCALE * wzero;

  // pass 2: re-read x row (cache-hot), emit xb (bf16) and out = wz*x
#pragma unroll
  for (int i = 0; i < 8; i++) {
    int k = (i * 64 + lane) * 4;
    float4 xv = *(const float4*)(xr + k);
    ushort4 ob;
    ob.x = f2bf(xv.x); ob.y = f2bf(xv.y);
    ob.z = f2bf(xv.z); ob.w = f2bf(xv.w);
    *(ushort4*)(xb + (size_t)n * HIDDEN + k) = ob;
    float4 o;
    o.x = wz * xv.x; o.y = wz * xv.y; o.z = wz * xv.z; o.w = wz * xv.w;
    *(float4*)(out + (size_t)n * HIDDEN + k) = o;
  }
}

// ---------------- partition: deterministic slot assignment, no atomics ----------
__global__ __launch_bounds__(1024) void partition_kernel(
    const signed char* __restrict__ tke, int* __restrict__ tok_list,
    int* __restrict__ tkr, int* __restrict__ counts, int* __restrict__ offsets) {
  __shared__ int scn[1024][NE];   // 32 KB
  __shared__ int soff[NE];
  int tid = threadIdx.x;
  int t4  = tid * 4;

  int w0 = *(const int*)(tke + t4);             // picks tt=0, tokens t4..t4+3
  int w1 = *(const int*)(tke + N_TOKENS + t4);  // picks tt=1

#pragma unroll
  for (int e = 0; e < NE; e++) scn[tid][e] = 0;
#pragma unroll
  for (int i = 0; i < 4; i++) {
    int e0 = (int)(signed char)(w0 >> (8 * i));
    int e1 = (int)(signed char)(w1 >> (8 * i));
    if (e0 >= 0) scn[tid][e0]++;
    if (e1 >= 0) scn[tid][e1]++;
  }
  int c[NE], orig[NE];
#pragma unroll
  for (int e = 0; e < NE; e++) { c[e] = scn[tid][e]; orig[e] = c[e]; }
  __syncthreads();

  for (int s = 1; s < 1024; s <<= 1) {
    int v[NE];
    bool act = (tid >= s);
    if (act) {
#pragma unroll
      for (int e = 0; e < NE; e++) v[e] = scn[tid - s][e];
    }
    __syncthreads();
    if (act) {
#pragma unroll
      for (int e = 0; e < NE; e++) { c[e] += v[e]; scn[tid][e] = c[e]; }
    }
    __syncthreads();
  }

  if (tid == 0) {
    int s = 0;
#pragma unroll
    for (int e = 0; e < NE; e++) {
      int cnt = scn[1023][e];
      counts[e] = cnt; offsets[e] = s; soff[e] = s; s += cnt;
    }
  }
  __syncthreads();

  // own-row cursors: within-expert exclusive prefix for this thread
#pragma unroll
  for (int e = 0; e < NE; e++) scn[tid][e] = c[e] - orig[e];

#pragma unroll
  for (int i = 0; i < 4; i++) {
    int n  = t4 + i;
    int e0 = (int)(signed char)(w0 >> (8 * i));
    int e1 = (int)(signed char)(w1 >> (8 * i));
    if (e0 >= 0) {
      int slot = scn[tid][e0]++;
      tok_list[e0 * N_TOKENS + slot] = n;
      tkr[n] = soff[e0] + slot;
    } else tkr[n] = 0;
    if (e1 >= 0) {
      int slot = scn[tid][e1]++;
      tok_list[e1 * N_TOKENS + slot] = n;
      tkr[N_TOKENS + n] = soff[e1] + slot;
    } else tkr[N_TOKENS + n] = 0;
  }
}

// LDS xor-swizzle (kills 8-way ds_read_b128 bank conflicts):
// physical 16B chunk p of row r holds logical chunk p ^ ((r>>1)&3).
// Staging (lane tid -> row tid>>2, slot tid&3): fetch global chunk
// (tid&3) ^ ((tid>>3)&3). Readers: physical chunk (lane>>4) ^ ((lane>>1)&3).
//
// __launch_bounds__(256,4): only ~900 blocks carry real work (count~820 ->
// 7 of 32 mt tiles x 16 jt x 8 e); at 2 blocks/CU they ran in two rounds
// with little cross-block overlap. 4 blocks/CU (LDS 32KB allows 5, VGPR 60
// allows 8 waves/SIMD) co-schedules all of them so cross-block MFMA hides
// each block's barrier drain (m114 mechanism).

// ---------------- gate_up grouped GEMM + fused SiLU*up ----------------
__global__ __launch_bounds__(256, 4) void gateup_kernel(
    const unsigned short* __restrict__ xb, const unsigned short* __restrict__ wgu,
    const int* __restrict__ counts, const int* __restrict__ offsets,
    const int* __restrict__ tok_list, unsigned short* __restrict__ h_buf) {
  int jt = blockIdx.x;  // 16: f-block of 64
  int mt = blockIdx.y;  // 32: token tile of 128
  int e  = blockIdx.z;  // 8
  int count = counts[e];
  if (mt * 128 >= count) return;

  __shared__ unsigned short As[2][128 * 32];
  __shared__ unsigned short Bs[2][128 * 32];

  int tid  = threadIdx.x;
  int lane = tid & 63;
  int wm = (tid >> 7) & 1;
  int wn = (tid >> 6) & 1;

  int row0 = tid >> 2, row1 = row0 + 64;
  int col8 = (((tid & 3) ^ ((tid >> 3) & 3)) * 8);  // swizzled source chunk

  const int* tl = tok_list + e * N_TOKENS;
  int t0 = tl[imin(mt * 128 + row0, count - 1)];
  int t1 = tl[imin(mt * 128 + row1, count - 1)];
  const unsigned short* ag0 = xb + (size_t)t0 * HIDDEN + col8;
  const unsigned short* ag1 = xb + (size_t)t1 * HIDDEN + col8;

  int wn0 = row0 >> 6, wi0 = row0 & 63;
  int wn1 = row1 >> 6, wi1 = row1 & 63;
  int br0 = (wi0 < 32) ? (jt * 64 + wn0 * 32 + wi0) : (1024 + jt * 64 + wn0 * 32 + (wi0 - 32));
  int br1 = (wi1 < 32) ? (jt * 64 + wn1 * 32 + wi1) : (1024 + jt * 64 + wn1 * 32 + (wi1 - 32));
  const unsigned short* bbase = wgu + (size_t)e * (2 * INTER) * HIDDEN;
  const unsigned short* bg0 = bbase + (size_t)br0 * HIDDEN + col8;
  const unsigned short* bg1 = bbase + (size_t)br1 * HIDDEN + col8;

  v4f acc[4][4];
#pragma unroll
  for (int i = 0; i < 4; i++)
#pragma unroll
    for (int j = 0; j < 4; j++) acc[i][j] = v4f{0.f, 0.f, 0.f, 0.f};

  int mrow = wm * 64 + (lane & 15);
  int nrow = wn * 64 + (lane & 15);
  int kcol = (((lane >> 4) ^ ((lane >> 1) & 3)) * 8);  // swizzled read chunk

  // prologue: stage tile 0 into buf 0
  gld_lds16(ag0, &As[0][(size_t)tid * 8]);
  gld_lds16(ag1, &As[0][2048 + (size_t)tid * 8]);
  gld_lds16(bg0, &Bs[0][(size_t)tid * 8]);
  gld_lds16(bg1, &Bs[0][2048 + (size_t)tid * 8]);
  ag0 += 32; ag1 += 32; bg0 += 32; bg1 += 32;
  __syncthreads();

  const int NK = HIDDEN / 32;
  for (int kt = 0; kt < NK; kt++) {
    int cur = kt & 1;
    if (kt + 1 < NK) {
      int nxt = cur ^ 1;
      gld_lds16(ag0, &As[nxt][(size_t)tid * 8]);
      gld_lds16(ag1, &As[nxt][2048 + (size_t)tid * 8]);
      gld_lds16(bg0, &Bs[nxt][(size_t)tid * 8]);
      gld_lds16(bg1, &Bs[nxt][2048 + (size_t)tid * 8]);
      ag0 += 32; ag1 += 32; bg0 += 32; bg1 += 32;
    }
    v8s a[4], b[4];
#pragma unroll
    for (int i = 0; i < 4; i++) a[i] = *(const v8s*)&As[cur][(mrow + i * 16) * 32 + kcol];
#pragma unroll
    for (int j = 0; j < 4; j++) b[j] = *(const v8s*)&Bs[cur][(nrow + j * 16) * 32 + kcol];
#pragma unroll
    for (int i = 0; i < 4; i++)
#pragma unroll
      for (int j = 0; j < 4; j++)
        acc[i][j] = __builtin_amdgcn_mfma_f32_16x16x32_bf16(a[i], b[j], acc[i][j], 0, 0, 0);
    __syncthreads();
  }

  int ocol  = lane & 15;
  int orow4 = (lane >> 4) * 4;
  int hoff  = offsets[e];
#pragma unroll
  for (int i = 0; i < 4; i++) {
#pragma unroll
    for (int r = 0; r < 4; r++) {
      int m = mt * 128 + wm * 64 + i * 16 + orow4 + r;
      if (m < count) {
        unsigned short* hrow = h_buf + (size_t)(hoff + m) * INTER;
#pragma unroll
        for (int j = 0; j < 2; j++) {
          float g = acc[i][j][r];
          float u = acc[i][j + 2][r];
          float hv = (g / (1.f + expf(-g))) * u;
          hrow[jt * 64 + wn * 32 + j * 16 + ocol] = f2bf(hv);
        }
      }
    }
  }
}

// ---------------- down grouped GEMM: plain f32 stores into y_buf (no atomics) ----
__global__ __launch_bounds__(256, 4) void down_kernel(
    const unsigned short* __restrict__ h_buf, const unsigned short* __restrict__ wd,
    const int* __restrict__ counts, const int* __restrict__ offsets,
    float* __restrict__ y_buf) {
  int nt = blockIdx.x;  // 16: out-col tile of 128
  int mt = blockIdx.y;  // 32
  int e  = blockIdx.z;  // 8
  int count = counts[e];
  if (mt * 128 >= count) return;

  __shared__ unsigned short As[2][128 * 32];
  __shared__ unsigned short Bs[2][128 * 32];

  int tid  = threadIdx.x;
  int lane = tid & 63;
  int wm = (tid >> 7) & 1;
  int wn = (tid >> 6) & 1;

  int row0 = tid >> 2, row1 = row0 + 64;
  int col8 = (((tid & 3) ^ ((tid >> 3) & 3)) * 8);
  int hoff = offsets[e];

  const unsigned short* ag0 =
      h_buf + (size_t)(hoff + imin(mt * 128 + row0, count - 1)) * INTER + col8;
  const unsigned short* ag1 =
      h_buf + (size_t)(hoff + imin(mt * 128 + row1, count - 1)) * INTER + col8;
  const unsigned short* bbase = wd + (size_t)e * HIDDEN * INTER;
  const unsigned short* bg0 = bbase + (size_t)(nt * 128 + row0) * INTER + col8;
  const unsigned short* bg1 = bbase + (size_t)(nt * 128 + row1) * INTER + col8;

  v4f acc[4][4];
#pragma unroll
  for (int i = 0; i < 4; i++)
#pragma unroll
    for (int j = 0; j < 4; j++) acc[i][j] = v4f{0.f, 0.f, 0.f, 0.f};

  int mrow = wm * 64 + (lane & 15);
  int nrow = wn * 64 + (lane & 15);
  int kcol = (((lane >> 4) ^ ((lane >> 1) & 3)) * 8);

  // prologue: stage tile 0 into buf 0
  gld_lds16(ag0, &As[0][(size_t)tid * 8]);
  gld_lds16(ag1, &As[0][2048 + (size_t)tid * 8]);
  gld_lds16(bg0, &Bs[0][(size_t)tid * 8]);
  gld_lds16(bg1, &Bs[0][2048 + (size_t)tid * 8]);
  ag0 += 32; ag1 += 32; bg0 += 32; bg1 += 32;
  __syncthreads();

  const int NK = INTER / 32;
  for (int kt = 0; kt < NK; kt++) {
    int cur = kt & 1;
    if (kt + 1 < NK) {
      int nxt = cur ^ 1;
      gld_lds16(ag0, &As[nxt][(size_t)tid * 8]);
      gld_lds16(ag1, &As[nxt][2048 + (size_t)tid * 8]);
      gld_lds16(bg0, &Bs[nxt][(size_t)tid * 8]);
      gld_lds16(bg1, &Bs[nxt][2048 + (size_t)tid * 8]);
      ag0 += 32; ag1 += 32; bg0 += 32; bg1 += 32;
    }
    v8s a[4], b[4];
#pragma unroll
    for (int i = 0; i < 4; i++) a[i] = *(const v8s*)&As[cur][(mrow + i * 16) * 32 + kcol];
#pragma unroll
    for (int j = 0; j < 4; j++) b[j] = *(const v8s*)&Bs[cur][(nrow + j * 16) * 32 + kcol];
#pragma unroll
    for (int i = 0; i < 4; i++)
#pragma unroll
      for (int j = 0; j < 4; j++)
        acc[i][j] = __builtin_amdgcn_mfma_f32_16x16x32_bf16(a[i], b[j], acc[i][j], 0, 0, 0);
    __syncthreads();
  }

  int ocol  = lane & 15;
  int orow4 = (lane >> 4) * 4;
#pragma unroll
  for (int i = 0; i < 4; i++) {
#pragma unroll
    for (int r = 0; r < 4; r++) {
      int m = mt * 128 + wm * 64 + i * 16 + orow4 + r;
      if (m < count) {
        float* yrow = y_buf + (size_t)(hoff + m) * HIDDEN + nt * 128 + wn * 64 + ocol;
#pragma unroll
        for (int j = 0; j < 4; j++) yrow[j * 16] = acc[i][j][r];
      }
    }
  }
}

// ---------------- gather: out += w1*y[r1] + w2*y[r2], one token per wave ----
__global__ __launch_bounds__(256, 4) void gather_kernel(
    const float* __restrict__ y_buf, const int* __restrict__ tkr,
    const float* __restrict__ tkw, float* __restrict__ out) {
  int tid  = threadIdx.x;
  int lane = tid & 63;
  int wid  = tid >> 6;
  int n    = blockIdx.x * 4 + wid;

  int r1 = tkr[n], r2 = tkr[N_TOKENS + n];
  float w1 = tkw[n], w2 = tkw[N_TOKENS + n];
  const float* y1 = y_buf + (size_t)r1 * HIDDEN;
  const float* y2 = y_buf + (size_t)r2 * HIDDEN;
  float* orow = out + (size_t)n * HIDDEN;

#pragma unroll
  for (int i = 0; i < 8; i++) {
    int k = (i * 64 + lane) * 4;
    float4 o = *(const float4*)(orow + k);
    float4 a = *(const float4*)(y1 + k);
    float4 b = *(const float4*)(y2 + k);
    o.x += w1 * a.x + w2 * b.x;
    o.y += w1 * a.y + w2 * b.y;
    o.z += w1 * a.z + w2 * b.z;
    o.w += w1 * a.w + w2 * b.w;
    *(float4*)(orow + k) = o;
  }
}

extern "C" void kernel_launch(void* const* d_in, const int* in_sizes, int n_in,
                              void* d_out, int out_size, void* d_ws, size_t ws_size,
                              hipStream_t stream) {
  const float* x   = (const float*)d_in[0];
  const float* rw  = (const float*)d_in[1];
  const float* cb  = (const float*)d_in[2];
  const float* wgu = (const float*)d_in[3];
  const float* wd  = (const float*)d_in[4];
  float* out = (float*)d_out;

  char* ws = (char*)d_ws;
  size_t off = 0;
  auto alloc = [&](size_t bytes) {
    void* p = ws + off;
    off += (bytes + 255) & ~(size_t)255;
    return p;
  };
  unsigned short* xb    = (unsigned short*)alloc((size_t)N_TOKENS * HIDDEN * 2);
  unsigned short* wgu_b = (unsigned short*)alloc((size_t)NE * 2 * INTER * HIDDEN * 2);
  unsigned short* wd_b  = (unsigned short*)alloc((size_t)NE * HIDDEN * INTER * 2);
  unsigned short* h_buf = (unsigned short*)alloc((size_t)2 * N_TOKENS * INTER * 2);
  int*   tok_list = (int*)alloc((size_t)NE * N_TOKENS * 4);
  signed char* tke = (signed char*)alloc((size_t)2 * N_TOKENS);
  int*   tkr      = (int*)alloc((size_t)2 * N_TOKENS * 4);
  float* tkw      = (float*)alloc((size_t)2 * N_TOKENS * 4);
  int*   counts   = (int*)alloc(256);
  int*   offsets  = (int*)alloc(256);
  // y_buf (8192 x 2048 f32 = 64 MiB) aliases wgu_b (same size): wgu_b is dead
  // after gateup_kernel; down writes y there, gather reads it, next iteration's
  // prep rewrites it. Stream-ordered, safe.
  float* y_buf = (float*)wgu_b;
  (void)ws_size; (void)in_sizes; (void)n_in; (void)out_size;

  prep_kernel<<<ROUTER_BLOCKS + CVT_BLOCKS, 256, 0, stream>>>(
      x, rw, cb, xb, tke, tkw, out, wgu, wd, wgu_b, wd_b);
  partition_kernel<<<1, 1024, 0, stream>>>(tke, tok_list, tkr, counts, offsets);
  gateup_kernel<<<dim3(16, 32, 8), 256, 0, stream>>>(xb, wgu_b, counts, offsets, tok_list, h_buf);
  down_kernel<<<dim3(16, 32, 8), 256, 0, stream>>>(h_buf, wd_b, counts, offsets, y_buf);
  gather_kernel<<<N_TOKENS / 4, 256, 0, stream>>>(y_buf, tkr, tkw, out);
}